// Round 1
// baseline (3367.963 us; speedup 1.0000x reference)
//
#include <hip/hip_runtime.h>

#define NN 50000
#define NE 600000
#define NB 512
#define HD 128
#define NMETA 27

__device__ __forceinline__ float relu(float x) { return fmaxf(x, 0.0f); }

// deg count: +1 per edge dst (fp32 exact for counts < 2^24)
__global__ __launch_bounds__(256) void k_count(const int* __restrict__ dst, float* __restrict__ deg) {
    int i = blockIdx.x * 256 + threadIdx.x;
    if (i < NE) atomicAdd(&deg[dst[i]], 1.0f);
}

// dinv[i] = rsqrt(deg_edges[i] + 1)  (self-loop guarantees >=1)
__global__ __launch_bounds__(256) void k_dinv(float* __restrict__ deg) {
    int i = blockIdx.x * 256 + threadIdx.x;
    if (i < NN) deg[i] = rsqrtf(deg[i] + 1.0f);
}

// norm[e] = dinv[src]*dinv[dst]
__global__ __launch_bounds__(256) void k_norm(const int* __restrict__ src, const int* __restrict__ dst,
                                              const float* __restrict__ dinv, float* __restrict__ norm) {
    int e = blockIdx.x * 256 + threadIdx.x;
    if (e < NE) norm[e] = dinv[src[e]] * dinv[dst[e]];
}

// T = X @ W   [NN,128] @ [128,128] fp32, vector ALU.
// 256 thr/block, 64 rows/block; thread = (ty=rowgroup of 8, tx=col quad).
__global__ __launch_bounds__(256) void k_gemm(const float* __restrict__ X, const float* __restrict__ W,
                                              float* __restrict__ T) {
    const int tx = threadIdx.x & 31;   // col quad: cols tx*4..tx*4+3
    const int ty = threadIdx.x >> 5;   // row group 0..7
    const int row0 = blockIdx.x * 64 + ty * 8;
    float acc[8][4] = {};
    int rows[8];
#pragma unroll
    for (int r = 0; r < 8; ++r) rows[r] = min(row0 + r, NN - 1);
    for (int k = 0; k < HD; k += 4) {
        float4 xv[8];
#pragma unroll
        for (int r = 0; r < 8; ++r)
            xv[r] = *reinterpret_cast<const float4*>(&X[(size_t)rows[r] * HD + k]);
#pragma unroll
        for (int kk = 0; kk < 4; ++kk) {
            float4 wv = *reinterpret_cast<const float4*>(&W[(k + kk) * HD + tx * 4]);
#pragma unroll
            for (int r = 0; r < 8; ++r) {
                float xs = (&xv[r].x)[kk];
                acc[r][0] = fmaf(xs, wv.x, acc[r][0]);
                acc[r][1] = fmaf(xs, wv.y, acc[r][1]);
                acc[r][2] = fmaf(xs, wv.z, acc[r][2]);
                acc[r][3] = fmaf(xs, wv.w, acc[r][3]);
            }
        }
    }
#pragma unroll
    for (int r = 0; r < 8; ++r) {
        int row = row0 + r;
        if (row < NN)
            *reinterpret_cast<float4*>(&T[(size_t)row * HD + tx * 4]) =
                make_float4(acc[r][0], acc[r][1], acc[r][2], acc[r][3]);
    }
}

// acc[dst] += T[src] * norm   — 32 threads per edge, 4 cols each
__global__ __launch_bounds__(256) void k_scatter(const int* __restrict__ src, const int* __restrict__ dst,
                                                 const float* __restrict__ norm, const float* __restrict__ T,
                                                 float* __restrict__ acc) {
    unsigned gid = blockIdx.x * 256u + threadIdx.x;
    int e = gid >> 5;
    if (e >= NE) return;
    int c = (gid & 31) * 4;
    int s = src[e], d = dst[e];
    float w = norm[e];
    float4 tv = *reinterpret_cast<const float4*>(&T[(size_t)s * HD + c]);
    float* ap = &acc[(size_t)d * HD + c];
    atomicAdd(ap + 0, tv.x * w);
    atomicAdd(ap + 1, tv.y * w);
    atomicAdd(ap + 2, tv.z * w);
    atomicAdd(ap + 3, tv.w * w);
}

// H = relu(acc + T*dinv^2 + b)   (self-loop folded in); in-place on acc is safe
__global__ __launch_bounds__(256) void k_finalize(const float* __restrict__ accb, const float* __restrict__ T,
                                                  const float* __restrict__ dinv, const float* __restrict__ b,
                                                  float* __restrict__ H) {
    unsigned gid = blockIdx.x * 256u + threadIdx.x;
    int row = gid >> 5;
    if (row >= NN) return;
    int c = (gid & 31) * 4;
    float di = dinv[row];
    float sl = di * di;
    float4 a = *reinterpret_cast<const float4*>(&accb[(size_t)row * HD + c]);
    float4 t = *reinterpret_cast<const float4*>(&T[(size_t)row * HD + c]);
    float4 bb = *reinterpret_cast<const float4*>(&b[c]);
    float4 o;
    o.x = relu(fmaf(t.x, sl, a.x) + bb.x);
    o.y = relu(fmaf(t.y, sl, a.y) + bb.y);
    o.z = relu(fmaf(t.z, sl, a.z) + bb.z);
    o.w = relu(fmaf(t.w, sl, a.w) + bb.w);
    *reinterpret_cast<float4*>(&H[(size_t)row * HD + c]) = o;
}

// mean-pool per graph: block g, thread c sums col c over nodes [lo,hi) (batch sorted)
__global__ __launch_bounds__(128) void k_pool(const float* __restrict__ H, const int* __restrict__ batch,
                                              float* __restrict__ emb) {
    int g = blockIdx.x;
    int l = 0, r = NN;
    while (l < r) { int m = (l + r) >> 1; if (batch[m] < g) l = m + 1; else r = m; }
    int lo = l;
    r = NN;
    while (l < r) { int m = (l + r) >> 1; if (batch[m] < g + 1) l = m + 1; else r = m; }
    int hi = l;
    int c = threadIdx.x;
    float s = 0.0f;
    for (int i = lo; i < hi; ++i) s += H[(size_t)i * HD + c];
    float cnt = (float)max(hi - lo, 1);
    emb[g * HD + c] = s / cnt;
}

// head: z = relu(emb@Wh1[:128] + meta@Wh1[128:155] + bh1); out = z@Wh2 + bh2
__global__ __launch_bounds__(128) void k_head(const float* __restrict__ emb, const float* __restrict__ meta,
                                              const float* __restrict__ Wh1, const float* __restrict__ bh1,
                                              const float* __restrict__ Wh2, const float* __restrict__ bh2,
                                              float* __restrict__ out) {
    int g = blockIdx.x;
    int j = threadIdx.x;
    float z = bh1[j];
    for (int k = 0; k < HD; ++k) z = fmaf(emb[g * HD + k], Wh1[k * HD + j], z);
    for (int k = 0; k < NMETA; ++k) z = fmaf(meta[g * NMETA + k], Wh1[(HD + k) * HD + j], z);
    z = relu(z);
    __shared__ float red[128];
    red[j] = z * Wh2[j];
    __syncthreads();
    for (int s = 64; s > 0; s >>= 1) {
        if (j < s) red[j] += red[j + s];
        __syncthreads();
    }
    if (j == 0) out[g] = red[0] + bh2[0];
}

extern "C" void kernel_launch(void* const* d_in, const int* in_sizes, int n_in,
                              void* d_out, int out_size, void* d_ws, size_t ws_size,
                              hipStream_t stream) {
    const float* x    = (const float*)d_in[0];
    const int*   ei   = (const int*)d_in[1];
    const int*   src  = ei;
    const int*   dst  = ei + NE;
    const int*   batch = (const int*)d_in[2];
    const float* meta = (const float*)d_in[3];
    const float* W1 = (const float*)d_in[4];  const float* b1 = (const float*)d_in[5];
    const float* W2 = (const float*)d_in[6];  const float* b2 = (const float*)d_in[7];
    const float* W3 = (const float*)d_in[8];  const float* b3 = (const float*)d_in[9];
    const float* Wh1 = (const float*)d_in[10]; const float* bh1 = (const float*)d_in[11];
    const float* Wh2 = (const float*)d_in[12]; const float* bh2 = (const float*)d_in[13];
    float* out = (float*)d_out;

    float* ws   = (float*)d_ws;
    float* dinv = ws;                          // NN
    float* norm = dinv + NN;                   // NE
    float* bufT = norm + NE;                   // NN*HD
    float* bufA = bufT + (size_t)NN * HD;      // NN*HD
    float* bufB = bufA + (size_t)NN * HD;      // NN*HD
    float* emb  = bufB + (size_t)NN * HD;      // NB*HD

    const int GEMM_GRID = (NN + 63) / 64;          // 782
    const int SC_GRID   = (NE * 32 + 255) / 256;   // 75000
    const int FIN_GRID  = (NN * 32 + 255) / 256;   // 6250

    // degree + norm
    hipMemsetAsync(dinv, 0, NN * sizeof(float), stream);
    k_count<<<(NE + 255) / 256, 256, 0, stream>>>(dst, dinv);
    k_dinv<<<(NN + 255) / 256, 256, 0, stream>>>(dinv);
    k_norm<<<(NE + 255) / 256, 256, 0, stream>>>(src, dst, dinv, norm);

    // layer 1: X=x -> H=bufA
    k_gemm<<<GEMM_GRID, 256, 0, stream>>>(x, W1, bufT);
    hipMemsetAsync(bufA, 0, (size_t)NN * HD * sizeof(float), stream);
    k_scatter<<<SC_GRID, 256, 0, stream>>>(src, dst, norm, bufT, bufA);
    k_finalize<<<FIN_GRID, 256, 0, stream>>>(bufA, bufT, dinv, b1, bufA);

    // layer 2: X=bufA -> H=bufB
    k_gemm<<<GEMM_GRID, 256, 0, stream>>>(bufA, W2, bufT);
    hipMemsetAsync(bufB, 0, (size_t)NN * HD * sizeof(float), stream);
    k_scatter<<<SC_GRID, 256, 0, stream>>>(src, dst, norm, bufT, bufB);
    k_finalize<<<FIN_GRID, 256, 0, stream>>>(bufB, bufT, dinv, b2, bufB);

    // layer 3: X=bufB -> H=bufA
    k_gemm<<<GEMM_GRID, 256, 0, stream>>>(bufB, W3, bufT);
    hipMemsetAsync(bufA, 0, (size_t)NN * HD * sizeof(float), stream);
    k_scatter<<<SC_GRID, 256, 0, stream>>>(src, dst, norm, bufT, bufA);
    k_finalize<<<FIN_GRID, 256, 0, stream>>>(bufA, bufT, dinv, b3, bufA);

    // pool + head
    k_pool<<<NB, 128, 0, stream>>>(bufA, batch, emb);
    k_head<<<NB, 128, 0, stream>>>(emb, meta, Wh1, bh1, Wh2, bh2, out);
}

// Round 3
// 626.400 us; speedup vs baseline: 5.3767x; 5.3767x over previous
//
#include <hip/hip_runtime.h>

#define NN 50000
#define NE 600000
#define NB 512
#define HD 128
#define NMETA 27

__device__ __forceinline__ float relu(float x) { return fmaxf(x, 0.0f); }

// count edges per dst (int atomics, build-once)
__global__ __launch_bounds__(256) void k_count(const int* __restrict__ dst, int* __restrict__ cnt) {
    int i = blockIdx.x * 256 + threadIdx.x;
    if (i < NE) atomicAdd(&cnt[dst[i]], 1);
}

// dinv[i] = rsqrt(cnt[i] + 1)   (self-loop guarantees deg >= 1)
__global__ __launch_bounds__(256) void k_dinv(const int* __restrict__ cnt, float* __restrict__ dinv) {
    int i = blockIdx.x * 256 + threadIdx.x;
    if (i < NN) dinv[i] = rsqrtf((float)cnt[i] + 1.0f);
}

// single-block exclusive scan of cnt[NN] -> rowptr[NN+1], cursor copy
__global__ __launch_bounds__(1024) void k_scan(const int* __restrict__ cnt, int* __restrict__ rowptr,
                                               int* __restrict__ cursor) {
    __shared__ int sums[1024];
    const int t = threadIdx.x;
    const int chunk = (NN + 1023) / 1024;  // 49
    const int lo = t * chunk, hi = min(lo + chunk, NN);
    int s = 0;
    for (int i = lo; i < hi; ++i) s += cnt[i];
    sums[t] = s;
    __syncthreads();
    for (int off = 1; off < 1024; off <<= 1) {
        int u = 0;
        if (t >= off) u = sums[t - off];
        __syncthreads();
        if (t >= off) sums[t] += u;
        __syncthreads();
    }
    int run = sums[t] - s;  // exclusive base for this chunk
    for (int i = lo; i < hi; ++i) {
        rowptr[i] = run;
        cursor[i] = run;
        run += cnt[i];
    }
    if (t == 1023) rowptr[NN] = sums[1023];  // == NE
}

// fill CSR: (src, norm) packed 8B per edge
__global__ __launch_bounds__(256) void k_fill(const int* __restrict__ src, const int* __restrict__ dst,
                                              const float* __restrict__ dinv, int* __restrict__ cursor,
                                              int2* __restrict__ csr_sw) {
    int e = blockIdx.x * 256 + threadIdx.x;
    if (e >= NE) return;
    int s = src[e], d = dst[e];
    int pos = atomicAdd(&cursor[d], 1);
    csr_sw[pos] = make_int2(s, __float_as_int(dinv[s] * dinv[d]));
}

// T = X @ W   [NN,128] @ [128,128] fp32, vector ALU. 64 rows/block.
__global__ __launch_bounds__(256) void k_gemm(const float* __restrict__ X, const float* __restrict__ W,
                                              float* __restrict__ T) {
    const int tx = threadIdx.x & 31;   // col quad
    const int ty = threadIdx.x >> 5;   // row group
    const int row0 = blockIdx.x * 64 + ty * 8;
    float acc[8][4] = {};
    int rows[8];
#pragma unroll
    for (int r = 0; r < 8; ++r) rows[r] = min(row0 + r, NN - 1);
    for (int k = 0; k < HD; k += 4) {
        float4 xv[8];
#pragma unroll
        for (int r = 0; r < 8; ++r)
            xv[r] = *reinterpret_cast<const float4*>(&X[(size_t)rows[r] * HD + k]);
#pragma unroll
        for (int kk = 0; kk < 4; ++kk) {
            float4 wv = *reinterpret_cast<const float4*>(&W[(k + kk) * HD + tx * 4]);
#pragma unroll
            for (int r = 0; r < 8; ++r) {
                float xs = (&xv[r].x)[kk];
                acc[r][0] = fmaf(xs, wv.x, acc[r][0]);
                acc[r][1] = fmaf(xs, wv.y, acc[r][1]);
                acc[r][2] = fmaf(xs, wv.z, acc[r][2]);
                acc[r][3] = fmaf(xs, wv.w, acc[r][3]);
            }
        }
    }
#pragma unroll
    for (int r = 0; r < 8; ++r) {
        int row = row0 + r;
        if (row < NN)
            *reinterpret_cast<float4*>(&T[(size_t)row * HD + tx * 4]) =
                make_float4(acc[r][0], acc[r][1], acc[r][2], acc[r][3]);
    }
}

// pull-based aggregation, fused self-loop + bias + relu:
// H[row] = relu( sum_{e in csr[row]} T[src_e]*w_e + T[row]*dinv[row]^2 + b )
// 32 lanes per row, 4 cols per lane.
__global__ __launch_bounds__(256) void k_gather(const int* __restrict__ rowptr, const int2* __restrict__ csr_sw,
                                                const float* __restrict__ T, const float* __restrict__ dinv,
                                                const float* __restrict__ b, float* __restrict__ H) {
    unsigned gid = blockIdx.x * 256u + threadIdx.x;
    int row = gid >> 5;
    if (row >= NN) return;
    int c = (gid & 31) * 4;
    int lo = rowptr[row], hi = rowptr[row + 1];
    float ax = 0.f, ay = 0.f, az = 0.f, aw = 0.f;
    for (int j = lo; j < hi; ++j) {
        int2 sw = csr_sw[j];
        float w = __int_as_float(sw.y);
        float4 tv = *reinterpret_cast<const float4*>(&T[(size_t)sw.x * HD + c]);
        ax = fmaf(tv.x, w, ax);
        ay = fmaf(tv.y, w, ay);
        az = fmaf(tv.z, w, az);
        aw = fmaf(tv.w, w, aw);
    }
    float di = dinv[row];
    float sl = di * di;
    float4 t = *reinterpret_cast<const float4*>(&T[(size_t)row * HD + c]);
    float4 bb = *reinterpret_cast<const float4*>(&b[c]);
    float4 o;
    o.x = relu(fmaf(t.x, sl, ax) + bb.x);
    o.y = relu(fmaf(t.y, sl, ay) + bb.y);
    o.z = relu(fmaf(t.z, sl, az) + bb.z);
    o.w = relu(fmaf(t.w, sl, aw) + bb.w);
    *reinterpret_cast<float4*>(&H[(size_t)row * HD + c]) = o;
}

// mean-pool per graph (batch sorted): block g, thread c
__global__ __launch_bounds__(128) void k_pool(const float* __restrict__ H, const int* __restrict__ batch,
                                              float* __restrict__ emb) {
    int g = blockIdx.x;
    int l = 0, r = NN;
    while (l < r) { int m = (l + r) >> 1; if (batch[m] < g) l = m + 1; else r = m; }
    int lo = l;
    r = NN;
    while (l < r) { int m = (l + r) >> 1; if (batch[m] < g + 1) l = m + 1; else r = m; }
    int hi = l;
    int c = threadIdx.x;
    float s = 0.0f;
    for (int i = lo; i < hi; ++i) s += H[(size_t)i * HD + c];
    float cnt = (float)max(hi - lo, 1);
    emb[g * HD + c] = s / cnt;
}

// head: z = relu(emb@Wh1[:128] + meta@Wh1[128:155] + bh1); out = z@Wh2 + bh2
__global__ __launch_bounds__(128) void k_head(const float* __restrict__ emb, const float* __restrict__ meta,
                                              const float* __restrict__ Wh1, const float* __restrict__ bh1,
                                              const float* __restrict__ Wh2, const float* __restrict__ bh2,
                                              float* __restrict__ out) {
    int g = blockIdx.x;
    int j = threadIdx.x;
    float z = bh1[j];
    for (int k = 0; k < HD; ++k) z = fmaf(emb[g * HD + k], Wh1[k * HD + j], z);
    for (int k = 0; k < NMETA; ++k) z = fmaf(meta[g * NMETA + k], Wh1[(HD + k) * HD + j], z);
    z = relu(z);
    __shared__ float red[128];
    red[j] = z * Wh2[j];
    __syncthreads();
    for (int s = 64; s > 0; s >>= 1) {
        if (j < s) red[j] += red[j + s];
        __syncthreads();
    }
    if (j == 0) out[g] = red[0] + bh2[0];
}

extern "C" void kernel_launch(void* const* d_in, const int* in_sizes, int n_in,
                              void* d_out, int out_size, void* d_ws, size_t ws_size,
                              hipStream_t stream) {
    const float* x     = (const float*)d_in[0];
    const int*   ei    = (const int*)d_in[1];
    const int*   src   = ei;
    const int*   dst   = ei + NE;
    const int*   batch = (const int*)d_in[2];
    const float* meta  = (const float*)d_in[3];
    const float* W1 = (const float*)d_in[4];  const float* b1 = (const float*)d_in[5];
    const float* W2 = (const float*)d_in[6];  const float* b2 = (const float*)d_in[7];
    const float* W3 = (const float*)d_in[8];  const float* b3 = (const float*)d_in[9];
    const float* Wh1 = (const float*)d_in[10]; const float* bh1 = (const float*)d_in[11];
    const float* Wh2 = (const float*)d_in[12]; const float* bh2 = (const float*)d_in[13];
    float* out = (float*)d_out;

    // workspace layout (16B-aligned sections)
    int2*  csr_sw = (int2*)d_ws;                         // NE * 8B
    int*   cnt    = (int*)(csr_sw + NE);                 // NN
    int*   rowptr = cnt + NN;                            // NN+8 pad
    int*   cursor = rowptr + NN + 8;                     // NN
    float* dinv   = (float*)(cursor + NN);               // NN
    float* bufT   = dinv + NN;                           // NN*HD
    float* bufA   = bufT + (size_t)NN * HD;              // NN*HD
    float* emb    = bufA + (size_t)NN * HD;              // NB*HD

    const int GEMM_GRID = (NN + 63) / 64;
    const int GATH_GRID = (NN * 32 + 255) / 256;

    // build CSR-by-dst (once per call)
    hipMemsetAsync(cnt, 0, NN * sizeof(int), stream);
    k_count<<<(NE + 255) / 256, 256, 0, stream>>>(dst, cnt);
    k_dinv<<<(NN + 255) / 256, 256, 0, stream>>>(cnt, dinv);
    k_scan<<<1, 1024, 0, stream>>>(cnt, rowptr, cursor);
    k_fill<<<(NE + 255) / 256, 256, 0, stream>>>(src, dst, dinv, cursor, csr_sw);

    // layer 1: x -> T -> A
    k_gemm<<<GEMM_GRID, 256, 0, stream>>>(x, W1, bufT);
    k_gather<<<GATH_GRID, 256, 0, stream>>>(rowptr, csr_sw, bufT, dinv, b1, bufA);
    // layer 2: A -> T -> A
    k_gemm<<<GEMM_GRID, 256, 0, stream>>>(bufA, W2, bufT);
    k_gather<<<GATH_GRID, 256, 0, stream>>>(rowptr, csr_sw, bufT, dinv, b2, bufA);
    // layer 3: A -> T -> A
    k_gemm<<<GEMM_GRID, 256, 0, stream>>>(bufA, W3, bufT);
    k_gather<<<GATH_GRID, 256, 0, stream>>>(rowptr, csr_sw, bufT, dinv, b3, bufA);

    // pool + head
    k_pool<<<NB, 128, 0, stream>>>(bufA, batch, emb);
    k_head<<<NB, 128, 0, stream>>>(emb, meta, Wh1, bh1, Wh2, bh2, out);
}

// Round 4
// 523.238 us; speedup vs baseline: 6.4368x; 1.1972x over previous
//
#include <hip/hip_runtime.h>

#define NN 50000
#define NE 600000
#define NB 512
#define HD 128
#define NMETA 27
#define SCAN_BLOCKS ((NN + 255) / 256)   // 196

__device__ __forceinline__ float relu(float x) { return fmaxf(x, 0.0f); }

// count edges per dst (int atomics, build-once)
__global__ __launch_bounds__(256) void k_count(const int* __restrict__ dst, int* __restrict__ cnt) {
    int i = blockIdx.x * 256 + threadIdx.x;
    if (i < NE) atomicAdd(&cnt[dst[i]], 1);
}

// phase A: per-block exclusive scan of cnt -> partial, block sums; fused dinv
__global__ __launch_bounds__(256) void k_scanA(const int* __restrict__ cnt, int* __restrict__ partial,
                                               int* __restrict__ blocksum, float* __restrict__ dinv) {
    const int t = threadIdx.x;
    const int i = blockIdx.x * 256 + t;
    int v = (i < NN) ? cnt[i] : 0;
    if (i < NN) dinv[i] = rsqrtf((float)v + 1.0f);
    __shared__ int s[256];
    s[t] = v;
    __syncthreads();
    for (int off = 1; off < 256; off <<= 1) {
        int u = (t >= off) ? s[t - off] : 0;
        __syncthreads();
        s[t] += u;
        __syncthreads();
    }
    if (i < NN) partial[i] = s[t] - v;          // exclusive within block
    if (t == 255) blocksum[blockIdx.x] = s[255]; // block total
}

// phase B: single small block scans the block sums -> exclusive block offsets
__global__ __launch_bounds__(256) void k_scanB(const int* __restrict__ blocksum, int* __restrict__ blockoff) {
    const int t = threadIdx.x;
    int v = (t < SCAN_BLOCKS) ? blocksum[t] : 0;
    __shared__ int s[256];
    s[t] = v;
    __syncthreads();
    for (int off = 1; off < 256; off <<= 1) {
        int u = (t >= off) ? s[t - off] : 0;
        __syncthreads();
        s[t] += u;
        __syncthreads();
    }
    if (t < SCAN_BLOCKS) blockoff[t] = s[t] - v;
}

// phase C: rowptr/cursor = partial + blockoff
__global__ __launch_bounds__(256) void k_scanC(const int* __restrict__ partial, const int* __restrict__ blockoff,
                                               int* __restrict__ rowptr, int* __restrict__ cursor) {
    const int i = blockIdx.x * 256 + threadIdx.x;
    if (i < NN) {
        int rp = partial[i] + blockoff[i >> 8];
        rowptr[i] = rp;
        cursor[i] = rp;
    }
    if (i == 0) rowptr[NN] = NE;
}

// fill CSR: (src, norm) packed 8B per edge
__global__ __launch_bounds__(256) void k_fill(const int* __restrict__ src, const int* __restrict__ dst,
                                              const float* __restrict__ dinv, int* __restrict__ cursor,
                                              int2* __restrict__ csr_sw) {
    int e = blockIdx.x * 256 + threadIdx.x;
    if (e >= NE) return;
    int s = src[e], d = dst[e];
    int pos = atomicAdd(&cursor[d], 1);
    csr_sw[pos] = make_int2(s, __float_as_int(dinv[s] * dinv[d]));
}

// T = X @ W   [NN,128] @ [128,128] fp32, vector ALU. 64 rows/block.
__global__ __launch_bounds__(256) void k_gemm(const float* __restrict__ X, const float* __restrict__ W,
                                              float* __restrict__ T) {
    const int tx = threadIdx.x & 31;   // col quad
    const int ty = threadIdx.x >> 5;   // row group
    const int row0 = blockIdx.x * 64 + ty * 8;
    float acc[8][4] = {};
    int rows[8];
#pragma unroll
    for (int r = 0; r < 8; ++r) rows[r] = min(row0 + r, NN - 1);
    for (int k = 0; k < HD; k += 4) {
        float4 xv[8];
#pragma unroll
        for (int r = 0; r < 8; ++r)
            xv[r] = *reinterpret_cast<const float4*>(&X[(size_t)rows[r] * HD + k]);
#pragma unroll
        for (int kk = 0; kk < 4; ++kk) {
            float4 wv = *reinterpret_cast<const float4*>(&W[(k + kk) * HD + tx * 4]);
#pragma unroll
            for (int r = 0; r < 8; ++r) {
                float xs = (&xv[r].x)[kk];
                acc[r][0] = fmaf(xs, wv.x, acc[r][0]);
                acc[r][1] = fmaf(xs, wv.y, acc[r][1]);
                acc[r][2] = fmaf(xs, wv.z, acc[r][2]);
                acc[r][3] = fmaf(xs, wv.w, acc[r][3]);
            }
        }
    }
#pragma unroll
    for (int r = 0; r < 8; ++r) {
        int row = row0 + r;
        if (row < NN)
            *reinterpret_cast<float4*>(&T[(size_t)row * HD + tx * 4]) =
                make_float4(acc[r][0], acc[r][1], acc[r][2], acc[r][3]);
    }
}

// pull-based aggregation, fused self-loop + bias + relu:
// H[row] = relu( sum_{e in csr[row]} T[src_e]*w_e + T[row]*dinv[row]^2 + b )
// 32 lanes per row, 4 cols per lane.
__global__ __launch_bounds__(256) void k_gather(const int* __restrict__ rowptr, const int2* __restrict__ csr_sw,
                                                const float* __restrict__ T, const float* __restrict__ dinv,
                                                const float* __restrict__ b, float* __restrict__ H) {
    unsigned gid = blockIdx.x * 256u + threadIdx.x;
    int row = gid >> 5;
    if (row >= NN) return;
    int c = (gid & 31) * 4;
    int lo = rowptr[row], hi = rowptr[row + 1];
    float ax = 0.f, ay = 0.f, az = 0.f, aw = 0.f;
    for (int j = lo; j < hi; ++j) {
        int2 sw = csr_sw[j];
        float w = __int_as_float(sw.y);
        float4 tv = *reinterpret_cast<const float4*>(&T[(size_t)sw.x * HD + c]);
        ax = fmaf(tv.x, w, ax);
        ay = fmaf(tv.y, w, ay);
        az = fmaf(tv.z, w, az);
        aw = fmaf(tv.w, w, aw);
    }
    float di = dinv[row];
    float sl = di * di;
    float4 t = *reinterpret_cast<const float4*>(&T[(size_t)row * HD + c]);
    float4 bb = *reinterpret_cast<const float4*>(&b[c]);
    float4 o;
    o.x = relu(fmaf(t.x, sl, ax) + bb.x);
    o.y = relu(fmaf(t.y, sl, ay) + bb.y);
    o.z = relu(fmaf(t.z, sl, az) + bb.z);
    o.w = relu(fmaf(t.w, sl, aw) + bb.w);
    *reinterpret_cast<float4*>(&H[(size_t)row * HD + c]) = o;
}

// mean-pool per graph (batch sorted): block g, thread c
__global__ __launch_bounds__(128) void k_pool(const float* __restrict__ H, const int* __restrict__ batch,
                                              float* __restrict__ emb) {
    int g = blockIdx.x;
    int l = 0, r = NN;
    while (l < r) { int m = (l + r) >> 1; if (batch[m] < g) l = m + 1; else r = m; }
    int lo = l;
    r = NN;
    while (l < r) { int m = (l + r) >> 1; if (batch[m] < g + 1) l = m + 1; else r = m; }
    int hi = l;
    int c = threadIdx.x;
    float s = 0.0f;
    for (int i = lo; i < hi; ++i) s += H[(size_t)i * HD + c];
    float cnt = (float)max(hi - lo, 1);
    emb[g * HD + c] = s / cnt;
}

// head: z = relu(emb@Wh1[:128] + meta@Wh1[128:155] + bh1); out = z@Wh2 + bh2
__global__ __launch_bounds__(128) void k_head(const float* __restrict__ emb, const float* __restrict__ meta,
                                              const float* __restrict__ Wh1, const float* __restrict__ bh1,
                                              const float* __restrict__ Wh2, const float* __restrict__ bh2,
                                              float* __restrict__ out) {
    int g = blockIdx.x;
    int j = threadIdx.x;
    float z = bh1[j];
    for (int k = 0; k < HD; ++k) z = fmaf(emb[g * HD + k], Wh1[k * HD + j], z);
    for (int k = 0; k < NMETA; ++k) z = fmaf(meta[g * NMETA + k], Wh1[(HD + k) * HD + j], z);
    z = relu(z);
    __shared__ float red[128];
    red[j] = z * Wh2[j];
    __syncthreads();
    for (int s = 64; s > 0; s >>= 1) {
        if (j < s) red[j] += red[j + s];
        __syncthreads();
    }
    if (j == 0) out[g] = red[0] + bh2[0];
}

extern "C" void kernel_launch(void* const* d_in, const int* in_sizes, int n_in,
                              void* d_out, int out_size, void* d_ws, size_t ws_size,
                              hipStream_t stream) {
    const float* x     = (const float*)d_in[0];
    const int*   ei    = (const int*)d_in[1];
    const int*   src   = ei;
    const int*   dst   = ei + NE;
    const int*   batch = (const int*)d_in[2];
    const float* meta  = (const float*)d_in[3];
    const float* W1 = (const float*)d_in[4];  const float* b1 = (const float*)d_in[5];
    const float* W2 = (const float*)d_in[6];  const float* b2 = (const float*)d_in[7];
    const float* W3 = (const float*)d_in[8];  const float* b3 = (const float*)d_in[9];
    const float* Wh1 = (const float*)d_in[10]; const float* bh1 = (const float*)d_in[11];
    const float* Wh2 = (const float*)d_in[12]; const float* bh2 = (const float*)d_in[13];
    float* out = (float*)d_out;

    // workspace layout (16B-aligned sections)
    int2*  csr_sw   = (int2*)d_ws;                       // NE * 8B
    int*   cnt      = (int*)(csr_sw + NE);               // NN
    int*   partial  = cnt + NN;                          // NN
    int*   blocksum = partial + NN;                      // SCAN_BLOCKS (+pad)
    int*   blockoff = blocksum + 256;                    // SCAN_BLOCKS (+pad)
    int*   rowptr   = blockoff + 256;                    // NN+1 (+pad)
    int*   cursor   = rowptr + NN + 8;                   // NN
    float* dinv     = (float*)(cursor + NN);             // NN
    float* bufT     = dinv + NN + 4;                     // NN*HD  (keep 16B align: NN%4==0)
    float* bufA     = bufT + (size_t)NN * HD;            // NN*HD
    float* emb      = bufA + (size_t)NN * HD;            // NB*HD

    const int GEMM_GRID = (NN + 63) / 64;
    const int GATH_GRID = (NN * 32 + 255) / 256;

    // build CSR-by-dst (once per call)
    hipMemsetAsync(cnt, 0, NN * sizeof(int), stream);
    k_count<<<(NE + 255) / 256, 256, 0, stream>>>(dst, cnt);
    k_scanA<<<SCAN_BLOCKS, 256, 0, stream>>>(cnt, partial, blocksum, dinv);
    k_scanB<<<1, 256, 0, stream>>>(blocksum, blockoff);
    k_scanC<<<SCAN_BLOCKS, 256, 0, stream>>>(partial, blockoff, rowptr, cursor);
    k_fill<<<(NE + 255) / 256, 256, 0, stream>>>(src, dst, dinv, cursor, csr_sw);

    // layer 1: x -> T -> A
    k_gemm<<<GEMM_GRID, 256, 0, stream>>>(x, W1, bufT);
    k_gather<<<GATH_GRID, 256, 0, stream>>>(rowptr, csr_sw, bufT, dinv, b1, bufA);
    // layer 2: A -> T -> A
    k_gemm<<<GEMM_GRID, 256, 0, stream>>>(bufA, W2, bufT);
    k_gather<<<GATH_GRID, 256, 0, stream>>>(rowptr, csr_sw, bufT, dinv, b2, bufA);
    // layer 3: A -> T -> A
    k_gemm<<<GEMM_GRID, 256, 0, stream>>>(bufA, W3, bufT);
    k_gather<<<GATH_GRID, 256, 0, stream>>>(rowptr, csr_sw, bufT, dinv, b3, bufA);

    // pool + head
    k_pool<<<NB, 128, 0, stream>>>(bufA, batch, emb);
    k_head<<<NB, 128, 0, stream>>>(emb, meta, Wh1, bh1, Wh2, bh2, out);
}

// Round 5
// 425.463 us; speedup vs baseline: 7.9160x; 1.2298x over previous
//
#include <hip/hip_runtime.h>

#define NN 50000
#define NE 600000
#define NB 512
#define HD 128
#define NMETA 27
#define SCAN_BLOCKS ((NN + 255) / 256)   // 196

typedef __attribute__((ext_vector_type(8))) short short8;   // 8 bf16 (A/B frag)
typedef __attribute__((ext_vector_type(4))) float f32x4;    // C/D frag

__device__ __forceinline__ float relu(float x) { return fmaxf(x, 0.0f); }

// fp32 -> bf16 round-to-nearest-even
__device__ __forceinline__ unsigned short f2bf(float f) {
    unsigned u = __float_as_uint(f);
    unsigned r = u + 0x7FFFu + ((u >> 16) & 1u);
    return (unsigned short)(r >> 16);
}
__device__ __forceinline__ float bf2f(unsigned short v) {
    return __uint_as_float(((unsigned)v) << 16);
}

// ---------------- CSR build ----------------
__global__ __launch_bounds__(256) void k_count(const int* __restrict__ dst, int* __restrict__ cnt) {
    int i = blockIdx.x * 256 + threadIdx.x;
    if (i < NE) atomicAdd(&cnt[dst[i]], 1);
}

__global__ __launch_bounds__(256) void k_scanA(const int* __restrict__ cnt, int* __restrict__ partial,
                                               int* __restrict__ blocksum, float* __restrict__ dinv) {
    const int t = threadIdx.x;
    const int i = blockIdx.x * 256 + t;
    int v = (i < NN) ? cnt[i] : 0;
    if (i < NN) dinv[i] = rsqrtf((float)v + 1.0f);
    __shared__ int s[256];
    s[t] = v;
    __syncthreads();
    for (int off = 1; off < 256; off <<= 1) {
        int u = (t >= off) ? s[t - off] : 0;
        __syncthreads();
        s[t] += u;
        __syncthreads();
    }
    if (i < NN) partial[i] = s[t] - v;
    if (t == 255) blocksum[blockIdx.x] = s[255];
}

__global__ __launch_bounds__(256) void k_scanB(const int* __restrict__ blocksum, int* __restrict__ blockoff) {
    const int t = threadIdx.x;
    int v = (t < SCAN_BLOCKS) ? blocksum[t] : 0;
    __shared__ int s[256];
    s[t] = v;
    __syncthreads();
    for (int off = 1; off < 256; off <<= 1) {
        int u = (t >= off) ? s[t - off] : 0;
        __syncthreads();
        s[t] += u;
        __syncthreads();
    }
    if (t < SCAN_BLOCKS) blockoff[t] = s[t] - v;
}

__global__ __launch_bounds__(256) void k_scanC(const int* __restrict__ partial, const int* __restrict__ blockoff,
                                               int* __restrict__ rowptr, int* __restrict__ cursor) {
    const int i = blockIdx.x * 256 + threadIdx.x;
    if (i < NN) {
        int rp = partial[i] + blockoff[i >> 8];
        rowptr[i] = rp;
        cursor[i] = rp;
    }
    if (i == 0) rowptr[NN] = NE;
}

__global__ __launch_bounds__(256) void k_fill(const int* __restrict__ src, const int* __restrict__ dst,
                                              const float* __restrict__ dinv, int* __restrict__ cursor,
                                              int2* __restrict__ csr_sw) {
    int e = blockIdx.x * 256 + threadIdx.x;
    if (e >= NE) return;
    int s = src[e], d = dst[e];
    int pos = atomicAdd(&cursor[d], 1);
    csr_sw[pos] = make_int2(s, __float_as_int(dinv[s] * dinv[d]));
}

// ---------------- fp32 -> bf16 casts ----------------
// x [NN*HD] f32 -> Xb bf16 (4 elems/thread)
__global__ __launch_bounds__(256) void k_cast_x(const float* __restrict__ X, unsigned short* __restrict__ Xb) {
    int i = blockIdx.x * 256 + threadIdx.x;     // quad index
    if (i >= NN * HD / 4) return;
    float4 v = *reinterpret_cast<const float4*>(X + (size_t)i * 4);
    ushort4 o;
    o.x = f2bf(v.x); o.y = f2bf(v.y); o.z = f2bf(v.z); o.w = f2bf(v.w);
    *reinterpret_cast<ushort4*>(Xb + (size_t)i * 4) = o;
}

// W [128][128] f32 row-major (k,n) -> Wt bf16 [n][k]
__global__ __launch_bounds__(256) void k_castWt(const float* __restrict__ W, unsigned short* __restrict__ Wt) {
    int i = blockIdx.x * 256 + threadIdx.x;
    if (i >= HD * HD) return;
    int k = i >> 7, n = i & 127;
    Wt[n * HD + k] = f2bf(W[i]);
}

// ---------------- MFMA GEMM: T = A @ W  (A bf16 [NN][HD], Wt bf16 [n][k]) ----------------
// block = 256 thr = 4 waves; wave handles 16 rows x 128 cols; 64 rows/block.
__global__ __launch_bounds__(256) void k_gemm_bf(const unsigned short* __restrict__ A,
                                                 const unsigned short* __restrict__ Wt,
                                                 unsigned short* __restrict__ T) {
    const int wave = threadIdx.x >> 6;
    const int lane = threadIdx.x & 63;
    const int lr = lane & 15;        // A row within tile / B col within tile / D col
    const int kh = lane >> 4;        // k-chunk selector (8 elems each)
    const int r0 = blockIdx.x * 64 + wave * 16;

    const unsigned short* arow = A + (size_t)min(r0 + lr, NN - 1) * HD + kh * 8;
    f32x4 acc[8] = {};  // 8 col-tiles of 16

#pragma unroll
    for (int kk = 0; kk < 4; ++kk) {     // K-steps of 32
        short8 af = *reinterpret_cast<const short8*>(arow + kk * 32);
#pragma unroll
        for (int n = 0; n < 8; ++n) {
            short8 bf = *reinterpret_cast<const short8*>(Wt + (size_t)(n * 16 + lr) * HD + kk * 32 + kh * 8);
            acc[n] = __builtin_amdgcn_mfma_f32_16x16x32_bf16(af, bf, acc[n], 0, 0, 0);
        }
    }
    // D: lane holds rows kh*4+r (r=0..3), col lr of each 16x16 tile
#pragma unroll
    for (int n = 0; n < 8; ++n) {
#pragma unroll
        for (int r = 0; r < 4; ++r) {
            int row = r0 + kh * 4 + r;
            if (row < NN) T[(size_t)row * HD + n * 16 + lr] = f2bf(acc[n][r]);
        }
    }
}

// ---------------- pull aggregation (bf16 in/out, fp32 acc) ----------------
__global__ __launch_bounds__(256) void k_gather(const int* __restrict__ rowptr, const int2* __restrict__ csr_sw,
                                                const unsigned short* __restrict__ T, const float* __restrict__ dinv,
                                                const float* __restrict__ b, unsigned short* __restrict__ H) {
    unsigned gid = blockIdx.x * 256u + threadIdx.x;
    int row = gid >> 5;
    if (row >= NN) return;
    int c = (gid & 31) * 4;
    int lo = rowptr[row], hi = rowptr[row + 1];
    float ax = 0.f, ay = 0.f, az = 0.f, aw = 0.f;
    for (int j = lo; j < hi; ++j) {
        int2 sw = csr_sw[j];
        float w = __int_as_float(sw.y);
        ushort4 tv = *reinterpret_cast<const ushort4*>(T + (size_t)sw.x * HD + c);
        ax = fmaf(bf2f(tv.x), w, ax);
        ay = fmaf(bf2f(tv.y), w, ay);
        az = fmaf(bf2f(tv.z), w, az);
        aw = fmaf(bf2f(tv.w), w, aw);
    }
    float di = dinv[row];
    float sl = di * di;
    ushort4 ts = *reinterpret_cast<const ushort4*>(T + (size_t)row * HD + c);
    float4 bb = *reinterpret_cast<const float4*>(b + c);
    ushort4 o;
    o.x = f2bf(relu(fmaf(bf2f(ts.x), sl, ax) + bb.x));
    o.y = f2bf(relu(fmaf(bf2f(ts.y), sl, ay) + bb.y));
    o.z = f2bf(relu(fmaf(bf2f(ts.z), sl, az) + bb.z));
    o.w = f2bf(relu(fmaf(bf2f(ts.w), sl, aw) + bb.w));
    *reinterpret_cast<ushort4*>(H + (size_t)row * HD + c) = o;
}

// ---------------- mean-pool (bf16 H -> fp32 emb) ----------------
__global__ __launch_bounds__(128) void k_pool(const unsigned short* __restrict__ H, const int* __restrict__ batch,
                                              float* __restrict__ emb) {
    int g = blockIdx.x;
    int l = 0, r = NN;
    while (l < r) { int m = (l + r) >> 1; if (batch[m] < g) l = m + 1; else r = m; }
    int lo = l;
    r = NN;
    while (l < r) { int m = (l + r) >> 1; if (batch[m] < g + 1) l = m + 1; else r = m; }
    int hi = l;
    int c = threadIdx.x;
    float s = 0.0f;
    for (int i = lo; i < hi; ++i) s += bf2f(H[(size_t)i * HD + c]);
    float cnt = (float)max(hi - lo, 1);
    emb[g * HD + c] = s / cnt;
}

// ---------------- head (fp32) ----------------
__global__ __launch_bounds__(128) void k_head(const float* __restrict__ emb, const float* __restrict__ meta,
                                              const float* __restrict__ Wh1, const float* __restrict__ bh1,
                                              const float* __restrict__ Wh2, const float* __restrict__ bh2,
                                              float* __restrict__ out) {
    int g = blockIdx.x;
    int j = threadIdx.x;
    float z = bh1[j];
    for (int k = 0; k < HD; ++k) z = fmaf(emb[g * HD + k], Wh1[k * HD + j], z);
    for (int k = 0; k < NMETA; ++k) z = fmaf(meta[g * NMETA + k], Wh1[(HD + k) * HD + j], z);
    z = relu(z);
    __shared__ float red[128];
    red[j] = z * Wh2[j];
    __syncthreads();
    for (int s = 64; s > 0; s >>= 1) {
        if (j < s) red[j] += red[j + s];
        __syncthreads();
    }
    if (j == 0) out[g] = red[0] + bh2[0];
}

extern "C" void kernel_launch(void* const* d_in, const int* in_sizes, int n_in,
                              void* d_out, int out_size, void* d_ws, size_t ws_size,
                              hipStream_t stream) {
    const float* x     = (const float*)d_in[0];
    const int*   ei    = (const int*)d_in[1];
    const int*   src   = ei;
    const int*   dst   = ei + NE;
    const int*   batch = (const int*)d_in[2];
    const float* meta  = (const float*)d_in[3];
    const float* W1 = (const float*)d_in[4];  const float* b1 = (const float*)d_in[5];
    const float* W2 = (const float*)d_in[6];  const float* b2 = (const float*)d_in[7];
    const float* W3 = (const float*)d_in[8];  const float* b3 = (const float*)d_in[9];
    const float* Wh1 = (const float*)d_in[10]; const float* bh1 = (const float*)d_in[11];
    const float* Wh2 = (const float*)d_in[12]; const float* bh2 = (const float*)d_in[13];
    float* out = (float*)d_out;

    // workspace layout
    int2*  csr_sw   = (int2*)d_ws;                        // NE*8B
    int*   cnt      = (int*)(csr_sw + NE);                // NN
    int*   partial  = cnt + NN;                           // NN
    int*   blocksum = partial + NN;                       // 256
    int*   blockoff = blocksum + 256;                     // 256
    int*   rowptr   = blockoff + 256;                     // NN+1 (pad 8)
    int*   cursor   = rowptr + NN + 8;                    // NN
    float* dinv     = (float*)(cursor + NN);              // NN
    float* emb      = dinv + NN;                          // NB*HD f32
    unsigned short* Xb  = (unsigned short*)(emb + NB * HD);   // NN*HD bf16
    unsigned short* Tb  = Xb + (size_t)NN * HD;               // NN*HD bf16
    unsigned short* Hb  = Tb + (size_t)NN * HD;               // NN*HD bf16
    unsigned short* Wt1 = Hb + (size_t)NN * HD;               // HD*HD bf16
    unsigned short* Wt2 = Wt1 + HD * HD;
    unsigned short* Wt3 = Wt2 + HD * HD;

    const int GEMM_GRID = (NN + 63) / 64;                 // 782
    const int GATH_GRID = (NN * 32 + 255) / 256;          // 6250
    const int CAST_GRID = (NN * HD / 4 + 255) / 256;      // 6250
    const int CWT_GRID  = (HD * HD + 255) / 256;          // 64

    // build CSR-by-dst
    hipMemsetAsync(cnt, 0, NN * sizeof(int), stream);
    k_count<<<(NE + 255) / 256, 256, 0, stream>>>(dst, cnt);
    k_scanA<<<SCAN_BLOCKS, 256, 0, stream>>>(cnt, partial, blocksum, dinv);
    k_scanB<<<1, 256, 0, stream>>>(blocksum, blockoff);
    k_scanC<<<SCAN_BLOCKS, 256, 0, stream>>>(partial, blockoff, rowptr, cursor);
    k_fill<<<(NE + 255) / 256, 256, 0, stream>>>(src, dst, dinv, cursor, csr_sw);

    // casts
    k_cast_x<<<CAST_GRID, 256, 0, stream>>>(x, Xb);
    k_castWt<<<CWT_GRID, 256, 0, stream>>>(W1, Wt1);
    k_castWt<<<CWT_GRID, 256, 0, stream>>>(W2, Wt2);
    k_castWt<<<CWT_GRID, 256, 0, stream>>>(W3, Wt3);

    // layer 1
    k_gemm_bf<<<GEMM_GRID, 256, 0, stream>>>(Xb, Wt1, Tb);
    k_gather<<<GATH_GRID, 256, 0, stream>>>(rowptr, csr_sw, Tb, dinv, b1, Hb);
    // layer 2
    k_gemm_bf<<<GEMM_GRID, 256, 0, stream>>>(Hb, Wt2, Tb);
    k_gather<<<GATH_GRID, 256, 0, stream>>>(rowptr, csr_sw, Tb, dinv, b2, Hb);
    // layer 3
    k_gemm_bf<<<GEMM_GRID, 256, 0, stream>>>(Hb, Wt3, Tb);
    k_gather<<<GATH_GRID, 256, 0, stream>>>(rowptr, csr_sw, Tb, dinv, b3, Hb);

    // pool + head
    k_pool<<<NB, 128, 0, stream>>>(Hb, batch, emb);
    k_head<<<NB, 128, 0, stream>>>(emb, meta, Wh1, bh1, Wh2, bh2, out);
}

// Round 6
// 344.162 us; speedup vs baseline: 9.7860x; 1.2362x over previous
//
#include <hip/hip_runtime.h>

#define NN 50000
#define NE 600000
#define NB 512
#define HD 128
#define NMETA 27
#define SCAN_BLOCKS ((NN + 255) / 256)   // 196

typedef __attribute__((ext_vector_type(8))) short short8;   // 8 bf16 (A/B frag)
typedef __attribute__((ext_vector_type(4))) float f32x4;    // C/D frag

__device__ __forceinline__ float relu(float x) { return fmaxf(x, 0.0f); }

// fp32 -> bf16 round-to-nearest-even
__device__ __forceinline__ unsigned short f2bf(float f) {
    unsigned u = __float_as_uint(f);
    unsigned r = u + 0x7FFFu + ((u >> 16) & 1u);
    return (unsigned short)(r >> 16);
}
__device__ __forceinline__ float bf2f(unsigned short v) {
    return __uint_as_float(((unsigned)v) << 16);
}

// ---------------- CSR build ----------------
__global__ __launch_bounds__(256) void k_count(const int* __restrict__ dst, int* __restrict__ cnt) {
    int i = blockIdx.x * 256 + threadIdx.x;
    if (i < NE) atomicAdd(&cnt[dst[i]], 1);
}

__global__ __launch_bounds__(256) void k_scanA(const int* __restrict__ cnt, int* __restrict__ partial,
                                               int* __restrict__ blocksum, float* __restrict__ dinv) {
    const int t = threadIdx.x;
    const int i = blockIdx.x * 256 + t;
    int v = (i < NN) ? cnt[i] : 0;
    if (i < NN) dinv[i] = rsqrtf((float)v + 1.0f);
    __shared__ int s[256];
    s[t] = v;
    __syncthreads();
    for (int off = 1; off < 256; off <<= 1) {
        int u = (t >= off) ? s[t - off] : 0;
        __syncthreads();
        s[t] += u;
        __syncthreads();
    }
    if (i < NN) partial[i] = s[t] - v;
    if (t == 255) blocksum[blockIdx.x] = s[255];
}

__global__ __launch_bounds__(256) void k_scanB(const int* __restrict__ blocksum, int* __restrict__ blockoff) {
    const int t = threadIdx.x;
    int v = (t < SCAN_BLOCKS) ? blocksum[t] : 0;
    __shared__ int s[256];
    s[t] = v;
    __syncthreads();
    for (int off = 1; off < 256; off <<= 1) {
        int u = (t >= off) ? s[t - off] : 0;
        __syncthreads();
        s[t] += u;
        __syncthreads();
    }
    if (t < SCAN_BLOCKS) blockoff[t] = s[t] - v;
}

__global__ __launch_bounds__(256) void k_scanC(const int* __restrict__ partial, const int* __restrict__ blockoff,
                                               int* __restrict__ rowptr, int* __restrict__ cursor) {
    const int i = blockIdx.x * 256 + threadIdx.x;
    if (i < NN) {
        int rp = partial[i] + blockoff[i >> 8];
        rowptr[i] = rp;
        cursor[i] = rp;
    }
    if (i == 0) rowptr[NN] = NE;
}

__global__ __launch_bounds__(256) void k_fill(const int* __restrict__ src, const int* __restrict__ dst,
                                              const float* __restrict__ dinv, int* __restrict__ cursor,
                                              int2* __restrict__ csr_sw) {
    int e = blockIdx.x * 256 + threadIdx.x;
    if (e >= NE) return;
    int s = src[e], d = dst[e];
    int pos = atomicAdd(&cursor[d], 1);
    csr_sw[pos] = make_int2(s, __float_as_int(dinv[s] * dinv[d]));
}

// ---------------- fp32 -> bf16 casts ----------------
__global__ __launch_bounds__(256) void k_cast_x(const float* __restrict__ X, unsigned short* __restrict__ Xb) {
    int i = blockIdx.x * 256 + threadIdx.x;     // quad index
    if (i >= NN * HD / 4) return;
    float4 v = *reinterpret_cast<const float4*>(X + (size_t)i * 4);
    ushort4 o;
    o.x = f2bf(v.x); o.y = f2bf(v.y); o.z = f2bf(v.z); o.w = f2bf(v.w);
    *reinterpret_cast<ushort4*>(Xb + (size_t)i * 4) = o;
}

// all three W [128][128] f32 row-major (k,n) -> Wt bf16 [n][k], one launch
__global__ __launch_bounds__(256) void k_castWt3(const float* __restrict__ W1, const float* __restrict__ W2,
                                                 const float* __restrict__ W3, unsigned short* __restrict__ Wt1,
                                                 unsigned short* __restrict__ Wt2, unsigned short* __restrict__ Wt3) {
    int i = blockIdx.x * 256 + threadIdx.x;
    if (i >= 3 * HD * HD) return;
    int which = i / (HD * HD);
    int r = i - which * (HD * HD);
    int k = r >> 7, n = r & 127;
    const float* W = (which == 0) ? W1 : (which == 1) ? W2 : W3;
    unsigned short* Wt = (which == 0) ? Wt1 : (which == 1) ? Wt2 : Wt3;
    Wt[n * HD + k] = f2bf(W[r]);
}

// ---------------- MFMA GEMM: T = A @ W ----------------
// Wt staged in LDS with XOR swizzle (T2): row-major [n][k] 256 B rows,
// read pattern = 16 lanes different rows same col-range -> swizzle needed.
// byte ^ ((row&7)<<4): rows r,r+8 alias -> 2-way conflict (free, m136).
__global__ __launch_bounds__(256) void k_gemm_bf(const unsigned short* __restrict__ A,
                                                 const unsigned short* __restrict__ Wt,
                                                 unsigned short* __restrict__ T) {
    __shared__ unsigned short Ws[HD * HD];      // 32 KB
    char* wsb = (char*)Ws;
    for (int i = threadIdx.x; i < HD * HD / 8; i += 256) {
        short8 v = ((const short8*)Wt)[i];
        int byte = i * 16;
        *(short8*)(wsb + (byte ^ (((byte >> 8) & 7) << 4))) = v;
    }
    __syncthreads();

    const int wave = threadIdx.x >> 6;
    const int lane = threadIdx.x & 63;
    const int lr = lane & 15;        // A row in tile / B col in tile / D col
    const int kh = lane >> 4;        // k-chunk selector (8 elems each)
    const int r0 = blockIdx.x * 64 + wave * 16;
    const unsigned short* arow = A + (size_t)min(r0 + lr, NN - 1) * HD + kh * 8;

    f32x4 acc[8] = {};               // 8 col-tiles of 16
#pragma unroll
    for (int kk = 0; kk < 4; ++kk) { // K-steps of 32
        short8 af = *reinterpret_cast<const short8*>(arow + kk * 32);
#pragma unroll
        for (int n = 0; n < 8; ++n) {
            int row = n * 16 + lr;
            int byte = row * 256 + kk * 64 + kh * 16;
            short8 bf = *(const short8*)(wsb + (byte ^ (((byte >> 8) & 7) << 4)));
            acc[n] = __builtin_amdgcn_mfma_f32_16x16x32_bf16(af, bf, acc[n], 0, 0, 0);
        }
    }
    // D: lane holds rows kh*4+r (r=0..3), col lr of each 16x16 tile (m89 mapping)
#pragma unroll
    for (int n = 0; n < 8; ++n) {
#pragma unroll
        for (int r = 0; r < 4; ++r) {
            int row = r0 + kh * 4 + r;
            if (row < NN) T[(size_t)row * HD + n * 16 + lr] = f2bf(acc[n][r]);
        }
    }
}

// ---------------- pull aggregation (bf16 in/out, fp32 acc), 4-way MLP ----------------
__global__ __launch_bounds__(256) void k_gather(const int* __restrict__ rowptr, const int2* __restrict__ csr_sw,
                                                const unsigned short* __restrict__ T, const float* __restrict__ dinv,
                                                const float* __restrict__ b, unsigned short* __restrict__ H) {
    unsigned gid = blockIdx.x * 256u + threadIdx.x;
    int row = gid >> 5;
    if (row >= NN) return;
    int c = (gid & 31) * 4;
    int lo = rowptr[row], hi = rowptr[row + 1];
    float ax = 0.f, ay = 0.f, az = 0.f, aw = 0.f;
    int j = lo;
    for (; j + 3 < hi; j += 4) {
        int2 s0 = csr_sw[j], s1 = csr_sw[j + 1], s2 = csr_sw[j + 2], s3 = csr_sw[j + 3];
        ushort4 t0 = *reinterpret_cast<const ushort4*>(T + (size_t)s0.x * HD + c);
        ushort4 t1 = *reinterpret_cast<const ushort4*>(T + (size_t)s1.x * HD + c);
        ushort4 t2 = *reinterpret_cast<const ushort4*>(T + (size_t)s2.x * HD + c);
        ushort4 t3 = *reinterpret_cast<const ushort4*>(T + (size_t)s3.x * HD + c);
        float w0 = __int_as_float(s0.y), w1 = __int_as_float(s1.y);
        float w2 = __int_as_float(s2.y), w3 = __int_as_float(s3.y);
        ax = fmaf(bf2f(t0.x), w0, ax); ay = fmaf(bf2f(t0.y), w0, ay);
        az = fmaf(bf2f(t0.z), w0, az); aw = fmaf(bf2f(t0.w), w0, aw);
        ax = fmaf(bf2f(t1.x), w1, ax); ay = fmaf(bf2f(t1.y), w1, ay);
        az = fmaf(bf2f(t1.z), w1, az); aw = fmaf(bf2f(t1.w), w1, aw);
        ax = fmaf(bf2f(t2.x), w2, ax); ay = fmaf(bf2f(t2.y), w2, ay);
        az = fmaf(bf2f(t2.z), w2, az); aw = fmaf(bf2f(t2.w), w2, aw);
        ax = fmaf(bf2f(t3.x), w3, ax); ay = fmaf(bf2f(t3.y), w3, ay);
        az = fmaf(bf2f(t3.z), w3, az); aw = fmaf(bf2f(t3.w), w3, aw);
    }
    for (; j < hi; ++j) {
        int2 sw = csr_sw[j];
        float w = __int_as_float(sw.y);
        ushort4 tv = *reinterpret_cast<const ushort4*>(T + (size_t)sw.x * HD + c);
        ax = fmaf(bf2f(tv.x), w, ax); ay = fmaf(bf2f(tv.y), w, ay);
        az = fmaf(bf2f(tv.z), w, az); aw = fmaf(bf2f(tv.w), w, aw);
    }
    float di = dinv[row];
    float sl = di * di;
    ushort4 ts = *reinterpret_cast<const ushort4*>(T + (size_t)row * HD + c);
    float4 bb = *reinterpret_cast<const float4*>(b + c);
    ushort4 o;
    o.x = f2bf(relu(fmaf(bf2f(ts.x), sl, ax) + bb.x));
    o.y = f2bf(relu(fmaf(bf2f(ts.y), sl, ay) + bb.y));
    o.z = f2bf(relu(fmaf(bf2f(ts.z), sl, az) + bb.z));
    o.w = f2bf(relu(fmaf(bf2f(ts.w), sl, aw) + bb.w));
    *reinterpret_cast<ushort4*>(H + (size_t)row * HD + c) = o;
}

// ---------------- mean-pool (bf16 H -> fp32 emb) ----------------
__global__ __launch_bounds__(128) void k_pool(const unsigned short* __restrict__ H, const int* __restrict__ batch,
                                              float* __restrict__ emb) {
    int g = blockIdx.x;
    int l = 0, r = NN;
    while (l < r) { int m = (l + r) >> 1; if (batch[m] < g) l = m + 1; else r = m; }
    int lo = l;
    r = NN;
    while (l < r) { int m = (l + r) >> 1; if (batch[m] < g + 1) l = m + 1; else r = m; }
    int hi = l;
    int c = threadIdx.x;
    float s = 0.0f;
    for (int i = lo; i < hi; ++i) s += bf2f(H[(size_t)i * HD + c]);
    float cnt = (float)max(hi - lo, 1);
    emb[g * HD + c] = s / cnt;
}

// ---------------- head (fp32) ----------------
__global__ __launch_bounds__(128) void k_head(const float* __restrict__ emb, const float* __restrict__ meta,
                                              const float* __restrict__ Wh1, const float* __restrict__ bh1,
                                              const float* __restrict__ Wh2, const float* __restrict__ bh2,
                                              float* __restrict__ out) {
    int g = blockIdx.x;
    int j = threadIdx.x;
    float z = bh1[j];
    for (int k = 0; k < HD; ++k) z = fmaf(emb[g * HD + k], Wh1[k * HD + j], z);
    for (int k = 0; k < NMETA; ++k) z = fmaf(meta[g * NMETA + k], Wh1[(HD + k) * HD + j], z);
    z = relu(z);
    __shared__ float red[128];
    red[j] = z * Wh2[j];
    __syncthreads();
    for (int s = 64; s > 0; s >>= 1) {
        if (j < s) red[j] += red[j + s];
        __syncthreads();
    }
    if (j == 0) out[g] = red[0] + bh2[0];
}

extern "C" void kernel_launch(void* const* d_in, const int* in_sizes, int n_in,
                              void* d_out, int out_size, void* d_ws, size_t ws_size,
                              hipStream_t stream) {
    const float* x     = (const float*)d_in[0];
    const int*   ei    = (const int*)d_in[1];
    const int*   src   = ei;
    const int*   dst   = ei + NE;
    const int*   batch = (const int*)d_in[2];
    const float* meta  = (const float*)d_in[3];
    const float* W1 = (const float*)d_in[4];  const float* b1 = (const float*)d_in[5];
    const float* W2 = (const float*)d_in[6];  const float* b2 = (const float*)d_in[7];
    const float* W3 = (const float*)d_in[8];  const float* b3 = (const float*)d_in[9];
    const float* Wh1 = (const float*)d_in[10]; const float* bh1 = (const float*)d_in[11];
    const float* Wh2 = (const float*)d_in[12]; const float* bh2 = (const float*)d_in[13];
    float* out = (float*)d_out;

    // workspace layout
    int2*  csr_sw   = (int2*)d_ws;                        // NE*8B
    int*   cnt      = (int*)(csr_sw + NE);                // NN
    int*   partial  = cnt + NN;                           // NN
    int*   blocksum = partial + NN;                       // 256
    int*   blockoff = blocksum + 256;                     // 256
    int*   rowptr   = blockoff + 256;                     // NN+1 (pad 8)
    int*   cursor   = rowptr + NN + 8;                    // NN
    float* dinv     = (float*)(cursor + NN);              // NN
    float* emb      = dinv + NN;                          // NB*HD f32
    unsigned short* Xb  = (unsigned short*)(emb + NB * HD);   // NN*HD bf16
    unsigned short* Tb  = Xb + (size_t)NN * HD;               // NN*HD bf16
    unsigned short* Hb  = Tb + (size_t)NN * HD;               // NN*HD bf16
    unsigned short* Wt1 = Hb + (size_t)NN * HD;               // HD*HD bf16
    unsigned short* Wt2 = Wt1 + HD * HD;
    unsigned short* Wt3 = Wt2 + HD * HD;

    const int GEMM_GRID = (NN + 63) / 64;                 // 782
    const int GATH_GRID = (NN * 32 + 255) / 256;          // 6250
    const int CAST_GRID = (NN * HD / 4 + 255) / 256;      // 1600
    const int CWT_GRID  = (3 * HD * HD + 255) / 256;      // 192

    // build CSR-by-dst
    hipMemsetAsync(cnt, 0, NN * sizeof(int), stream);
    k_count<<<(NE + 255) / 256, 256, 0, stream>>>(dst, cnt);
    k_scanA<<<SCAN_BLOCKS, 256, 0, stream>>>(cnt, partial, blocksum, dinv);
    k_scanB<<<1, 256, 0, stream>>>(blocksum, blockoff);
    k_scanC<<<SCAN_BLOCKS, 256, 0, stream>>>(partial, blockoff, rowptr, cursor);
    k_fill<<<(NE + 255) / 256, 256, 0, stream>>>(src, dst, dinv, cursor, csr_sw);

    // casts
    k_cast_x<<<CAST_GRID, 256, 0, stream>>>(x, Xb);
    k_castWt3<<<CWT_GRID, 256, 0, stream>>>(W1, W2, W3, Wt1, Wt2, Wt3);

    // layer 1
    k_gemm_bf<<<GEMM_GRID, 256, 0, stream>>>(Xb, Wt1, Tb);
    k_gather<<<GATH_GRID, 256, 0, stream>>>(rowptr, csr_sw, Tb, dinv, b1, Hb);
    // layer 2
    k_gemm_bf<<<GEMM_GRID, 256, 0, stream>>>(Hb, Wt2, Tb);
    k_gather<<<GATH_GRID, 256, 0, stream>>>(rowptr, csr_sw, Tb, dinv, b2, Hb);
    // layer 3
    k_gemm_bf<<<GEMM_GRID, 256, 0, stream>>>(Hb, Wt3, Tb);
    k_gather<<<GATH_GRID, 256, 0, stream>>>(rowptr, csr_sw, Tb, dinv, b3, Hb);

    // pool + head
    k_pool<<<NB, 128, 0, stream>>>(Hb, batch, emb);
    k_head<<<NB, 128, 0, stream>>>(emb, meta, Wh1, bh1, Wh2, bh2, out);
}

// Round 7
// 337.009 us; speedup vs baseline: 9.9937x; 1.0212x over previous
//
#include <hip/hip_runtime.h>

#define NN 50000
#define NE 600000
#define NB 512
#define HD 128
#define NMETA 27
#define SCAN_BLOCKS ((NN + 255) / 256)   // 196

typedef __attribute__((ext_vector_type(8))) short short8;   // 8 bf16 (A/B frag)
typedef __attribute__((ext_vector_type(4))) float f32x4;    // C/D frag

__device__ __forceinline__ float relu(float x) { return fmaxf(x, 0.0f); }

// fp32 -> bf16 round-to-nearest-even
__device__ __forceinline__ unsigned short f2bf(float f) {
    unsigned u = __float_as_uint(f);
    unsigned r = u + 0x7FFFu + ((u >> 16) & 1u);
    return (unsigned short)(r >> 16);
}
__device__ __forceinline__ float bf2f(unsigned short v) {
    return __uint_as_float(((unsigned)v) << 16);
}

// ---------------- CSR build ----------------
__global__ __launch_bounds__(256) void k_count(const int* __restrict__ dst, int* __restrict__ cnt) {
    int i = blockIdx.x * 256 + threadIdx.x;
    if (i < NE) atomicAdd(&cnt[dst[i]], 1);
}

__global__ __launch_bounds__(256) void k_scanA(const int* __restrict__ cnt, int* __restrict__ partial,
                                               int* __restrict__ blocksum, float* __restrict__ dinv) {
    const int t = threadIdx.x;
    const int i = blockIdx.x * 256 + t;
    int v = (i < NN) ? cnt[i] : 0;
    if (i < NN) dinv[i] = rsqrtf((float)v + 1.0f);
    __shared__ int s[256];
    s[t] = v;
    __syncthreads();
    for (int off = 1; off < 256; off <<= 1) {
        int u = (t >= off) ? s[t - off] : 0;
        __syncthreads();
        s[t] += u;
        __syncthreads();
    }
    if (i < NN) partial[i] = s[t] - v;
    if (t == 255) blocksum[blockIdx.x] = s[255];
}

__global__ __launch_bounds__(256) void k_scanB(const int* __restrict__ blocksum, int* __restrict__ blockoff) {
    const int t = threadIdx.x;
    int v = (t < SCAN_BLOCKS) ? blocksum[t] : 0;
    __shared__ int s[256];
    s[t] = v;
    __syncthreads();
    for (int off = 1; off < 256; off <<= 1) {
        int u = (t >= off) ? s[t - off] : 0;
        __syncthreads();
        s[t] += u;
        __syncthreads();
    }
    if (t < SCAN_BLOCKS) blockoff[t] = s[t] - v;
}

__global__ __launch_bounds__(256) void k_scanC(const int* __restrict__ partial, const int* __restrict__ blockoff,
                                               int* __restrict__ rowptr, int* __restrict__ cursor) {
    const int i = blockIdx.x * 256 + threadIdx.x;
    if (i < NN) {
        int rp = partial[i] + blockoff[i >> 8];
        rowptr[i] = rp;
        cursor[i] = rp;
    }
    if (i == 0) rowptr[NN] = NE;
}

__global__ __launch_bounds__(256) void k_fill(const int* __restrict__ src, const int* __restrict__ dst,
                                              const float* __restrict__ dinv, int* __restrict__ cursor,
                                              int2* __restrict__ csr_sw) {
    int e = blockIdx.x * 256 + threadIdx.x;
    if (e >= NE) return;
    int s = src[e], d = dst[e];
    int pos = atomicAdd(&cursor[d], 1);
    csr_sw[pos] = make_int2(s, __float_as_int(dinv[s] * dinv[d]));
}

// all three W [128][128] f32 row-major (k,n) -> Wt bf16 [n][k], one launch
__global__ __launch_bounds__(256) void k_castWt3(const float* __restrict__ W1, const float* __restrict__ W2,
                                                 const float* __restrict__ W3, unsigned short* __restrict__ Wt1,
                                                 unsigned short* __restrict__ Wt2, unsigned short* __restrict__ Wt3) {
    int i = blockIdx.x * 256 + threadIdx.x;
    if (i >= 3 * HD * HD) return;
    int which = i / (HD * HD);
    int r = i - which * (HD * HD);
    int k = r >> 7, n = r & 127;
    const float* W = (which == 0) ? W1 : (which == 1) ? W2 : W3;
    unsigned short* Wt = (which == 0) ? Wt1 : (which == 1) ? Wt2 : Wt3;
    Wt[n * HD + k] = f2bf(W[r]);
}

// ---------------- layer-1 GEMM: T1 = cast(x) @ W1, x fp32 read directly ----------------
// 256 thr = 4 waves, 64 rows/block; Wt staged in LDS with XOR swizzle (T2).
__global__ __launch_bounds__(256) void k_gemm_x(const float* __restrict__ X,
                                                const unsigned short* __restrict__ Wt,
                                                unsigned short* __restrict__ T) {
    __shared__ unsigned short Ws[HD * HD];      // 32 KB
    char* wsb = (char*)Ws;
    for (int i = threadIdx.x; i < HD * HD / 8; i += 256) {
        short8 v = ((const short8*)Wt)[i];
        int byte = i * 16;
        *(short8*)(wsb + (byte ^ (((byte >> 8) & 7) << 4))) = v;
    }
    __syncthreads();

    const int wave = threadIdx.x >> 6;
    const int lane = threadIdx.x & 63;
    const int lr = lane & 15;
    const int kh = lane >> 4;
    const int r0 = blockIdx.x * 64 + wave * 16;
    const float* arow = X + (size_t)min(r0 + lr, NN - 1) * HD + kh * 8;

    f32x4 acc[8] = {};
#pragma unroll
    for (int kk = 0; kk < 4; ++kk) {
        float4 a0 = *reinterpret_cast<const float4*>(arow + kk * 32);
        float4 a1 = *reinterpret_cast<const float4*>(arow + kk * 32 + 4);
        short8 af;
        af[0] = (short)f2bf(a0.x); af[1] = (short)f2bf(a0.y);
        af[2] = (short)f2bf(a0.z); af[3] = (short)f2bf(a0.w);
        af[4] = (short)f2bf(a1.x); af[5] = (short)f2bf(a1.y);
        af[6] = (short)f2bf(a1.z); af[7] = (short)f2bf(a1.w);
#pragma unroll
        for (int n = 0; n < 8; ++n) {
            int byte = (n * 16 + lr) * 256 + kk * 64 + kh * 16;
            short8 bf = *(const short8*)(wsb + (byte ^ (((byte >> 8) & 7) << 4)));
            acc[n] = __builtin_amdgcn_mfma_f32_16x16x32_bf16(af, bf, acc[n], 0, 0, 0);
        }
    }
#pragma unroll
    for (int n = 0; n < 8; ++n) {
#pragma unroll
        for (int r = 0; r < 4; ++r) {
            int row = r0 + kh * 4 + r;
            if (row < NN) T[(size_t)row * HD + n * 16 + lr] = f2bf(acc[n][r]);
        }
    }
}

// ---------------- fused gather(T_in)->H(LDS) -> T_out = H @ Wt_next ----------------
// 512 thr = 8 waves, 16 rows/block, grid = NN/16 = 3125 exactly.
// Phase 1: 16 rows gathered in parallel (32 lanes/row, 4 cols/lane) -> LDS (swizzled).
// Phase 2: wave w computes 16-col n-tile w: 4 MFMAs, A from LDS, B from L2.
__global__ __launch_bounds__(512, 8) void k_fused(const int* __restrict__ rowptr, const int2* __restrict__ csr_sw,
                                                  const unsigned short* __restrict__ Tin, const float* __restrict__ dinv,
                                                  const float* __restrict__ b, const unsigned short* __restrict__ Wt,
                                                  unsigned short* __restrict__ Tout) {
    __shared__ unsigned short Hs[16 * HD];      // 4 KB
    char* hsb = (char*)Hs;

    // ---- phase 1: gather 16 rows ----
    {
        const int wrow = threadIdx.x >> 5;            // 0..15
        const int row = blockIdx.x * 16 + wrow;       // always < NN (50000 = 3125*16)
        const int c = (threadIdx.x & 31) * 4;
        int lo = rowptr[row], hi = rowptr[row + 1];
        float ax = 0.f, ay = 0.f, az = 0.f, aw = 0.f;
        int j = lo;
        for (; j + 3 < hi; j += 4) {
            int2 s0 = csr_sw[j], s1 = csr_sw[j + 1], s2 = csr_sw[j + 2], s3 = csr_sw[j + 3];
            ushort4 t0 = *reinterpret_cast<const ushort4*>(Tin + (size_t)s0.x * HD + c);
            ushort4 t1 = *reinterpret_cast<const ushort4*>(Tin + (size_t)s1.x * HD + c);
            ushort4 t2 = *reinterpret_cast<const ushort4*>(Tin + (size_t)s2.x * HD + c);
            ushort4 t3 = *reinterpret_cast<const ushort4*>(Tin + (size_t)s3.x * HD + c);
            float w0 = __int_as_float(s0.y), w1 = __int_as_float(s1.y);
            float w2 = __int_as_float(s2.y), w3 = __int_as_float(s3.y);
            ax = fmaf(bf2f(t0.x), w0, ax); ay = fmaf(bf2f(t0.y), w0, ay);
            az = fmaf(bf2f(t0.z), w0, az); aw = fmaf(bf2f(t0.w), w0, aw);
            ax = fmaf(bf2f(t1.x), w1, ax); ay = fmaf(bf2f(t1.y), w1, ay);
            az = fmaf(bf2f(t1.z), w1, az); aw = fmaf(bf2f(t1.w), w1, aw);
            ax = fmaf(bf2f(t2.x), w2, ax); ay = fmaf(bf2f(t2.y), w2, ay);
            az = fmaf(bf2f(t2.z), w2, az); aw = fmaf(bf2f(t2.w), w2, aw);
            ax = fmaf(bf2f(t3.x), w3, ax); ay = fmaf(bf2f(t3.y), w3, ay);
            az = fmaf(bf2f(t3.z), w3, az); aw = fmaf(bf2f(t3.w), w3, aw);
        }
        for (; j < hi; ++j) {
            int2 sw = csr_sw[j];
            float w = __int_as_float(sw.y);
            ushort4 tv = *reinterpret_cast<const ushort4*>(Tin + (size_t)sw.x * HD + c);
            ax = fmaf(bf2f(tv.x), w, ax); ay = fmaf(bf2f(tv.y), w, ay);
            az = fmaf(bf2f(tv.z), w, az); aw = fmaf(bf2f(tv.w), w, aw);
        }
        float di = dinv[row];
        float sl = di * di;
        ushort4 ts = *reinterpret_cast<const ushort4*>(Tin + (size_t)row * HD + c);
        float4 bb = *reinterpret_cast<const float4*>(b + c);
        ushort4 o;
        o.x = f2bf(relu(fmaf(bf2f(ts.x), sl, ax) + bb.x));
        o.y = f2bf(relu(fmaf(bf2f(ts.y), sl, ay) + bb.y));
        o.z = f2bf(relu(fmaf(bf2f(ts.z), sl, az) + bb.z));
        o.w = f2bf(relu(fmaf(bf2f(ts.w), sl, aw) + bb.w));
        int byte = wrow * 256 + (threadIdx.x & 31) * 8;
        *(ushort4*)(hsb + (byte ^ (((byte >> 8) & 7) << 4))) = o;
    }
    __syncthreads();

    // ---- phase 2: T_out tile = H_tile @ Wt ----
    {
        const int w = threadIdx.x >> 6;       // n-tile 0..7
        const int lane = threadIdx.x & 63;
        const int lr = lane & 15;
        const int kh = lane >> 4;
        f32x4 acc = {};
#pragma unroll
        for (int kk = 0; kk < 4; ++kk) {
            int byte = lr * 256 + kk * 64 + kh * 16;
            short8 af = *(const short8*)(hsb + (byte ^ (((byte >> 8) & 7) << 4)));
            short8 bf = *reinterpret_cast<const short8*>(Wt + (size_t)(w * 16 + lr) * HD + kk * 32 + kh * 8);
            acc = __builtin_amdgcn_mfma_f32_16x16x32_bf16(af, bf, acc, 0, 0, 0);
        }
#pragma unroll
        for (int r = 0; r < 4; ++r) {
            int row = blockIdx.x * 16 + kh * 4 + r;
            Tout[(size_t)row * HD + w * 16 + lr] = f2bf(acc[r]);
        }
    }
}

// ---------------- final pull aggregation (T3 -> H3 global) ----------------
__global__ __launch_bounds__(256) void k_gather(const int* __restrict__ rowptr, const int2* __restrict__ csr_sw,
                                                const unsigned short* __restrict__ T, const float* __restrict__ dinv,
                                                const float* __restrict__ b, unsigned short* __restrict__ H) {
    unsigned gid = blockIdx.x * 256u + threadIdx.x;
    int row = gid >> 5;
    if (row >= NN) return;
    int c = (gid & 31) * 4;
    int lo = rowptr[row], hi = rowptr[row + 1];
    float ax = 0.f, ay = 0.f, az = 0.f, aw = 0.f;
    int j = lo;
    for (; j + 3 < hi; j += 4) {
        int2 s0 = csr_sw[j], s1 = csr_sw[j + 1], s2 = csr_sw[j + 2], s3 = csr_sw[j + 3];
        ushort4 t0 = *reinterpret_cast<const ushort4*>(T + (size_t)s0.x * HD + c);
        ushort4 t1 = *reinterpret_cast<const ushort4*>(T + (size_t)s1.x * HD + c);
        ushort4 t2 = *reinterpret_cast<const ushort4*>(T + (size_t)s2.x * HD + c);
        ushort4 t3 = *reinterpret_cast<const ushort4*>(T + (size_t)s3.x * HD + c);
        float w0 = __int_as_float(s0.y), w1 = __int_as_float(s1.y);
        float w2 = __int_as_float(s2.y), w3 = __int_as_float(s3.y);
        ax = fmaf(bf2f(t0.x), w0, ax); ay = fmaf(bf2f(t0.y), w0, ay);
        az = fmaf(bf2f(t0.z), w0, az); aw = fmaf(bf2f(t0.w), w0, aw);
        ax = fmaf(bf2f(t1.x), w1, ax); ay = fmaf(bf2f(t1.y), w1, ay);
        az = fmaf(bf2f(t1.z), w1, az); aw = fmaf(bf2f(t1.w), w1, aw);
        ax = fmaf(bf2f(t2.x), w2, ax); ay = fmaf(bf2f(t2.y), w2, ay);
        az = fmaf(bf2f(t2.z), w2, az); aw = fmaf(bf2f(t2.w), w2, aw);
        ax = fmaf(bf2f(t3.x), w3, ax); ay = fmaf(bf2f(t3.y), w3, ay);
        az = fmaf(bf2f(t3.z), w3, az); aw = fmaf(bf2f(t3.w), w3, aw);
    }
    for (; j < hi; ++j) {
        int2 sw = csr_sw[j];
        float w = __int_as_float(sw.y);
        ushort4 tv = *reinterpret_cast<const ushort4*>(T + (size_t)sw.x * HD + c);
        ax = fmaf(bf2f(tv.x), w, ax); ay = fmaf(bf2f(tv.y), w, ay);
        az = fmaf(bf2f(tv.z), w, az); aw = fmaf(bf2f(tv.w), w, aw);
    }
    float di = dinv[row];
    float sl = di * di;
    ushort4 ts = *reinterpret_cast<const ushort4*>(T + (size_t)row * HD + c);
    float4 bb = *reinterpret_cast<const float4*>(b + c);
    ushort4 o;
    o.x = f2bf(relu(fmaf(bf2f(ts.x), sl, ax) + bb.x));
    o.y = f2bf(relu(fmaf(bf2f(ts.y), sl, ay) + bb.y));
    o.z = f2bf(relu(fmaf(bf2f(ts.z), sl, az) + bb.z));
    o.w = f2bf(relu(fmaf(bf2f(ts.w), sl, aw) + bb.w));
    *reinterpret_cast<ushort4*>(H + (size_t)row * HD + c) = o;
}

// ---------------- mean-pool (bf16 H -> fp32 emb) ----------------
__global__ __launch_bounds__(128) void k_pool(const unsigned short* __restrict__ H, const int* __restrict__ batch,
                                              float* __restrict__ emb) {
    int g = blockIdx.x;
    int l = 0, r = NN;
    while (l < r) { int m = (l + r) >> 1; if (batch[m] < g) l = m + 1; else r = m; }
    int lo = l;
    r = NN;
    while (l < r) { int m = (l + r) >> 1; if (batch[m] < g + 1) l = m + 1; else r = m; }
    int hi = l;
    int c = threadIdx.x;
    float s = 0.0f;
    for (int i = lo; i < hi; ++i) s += bf2f(H[(size_t)i * HD + c]);
    float cnt = (float)max(hi - lo, 1);
    emb[g * HD + c] = s / cnt;
}

// ---------------- head (fp32) ----------------
__global__ __launch_bounds__(128) void k_head(const float* __restrict__ emb, const float* __restrict__ meta,
                                              const float* __restrict__ Wh1, const float* __restrict__ bh1,
                                              const float* __restrict__ Wh2, const float* __restrict__ bh2,
                                              float* __restrict__ out) {
    int g = blockIdx.x;
    int j = threadIdx.x;
    float z = bh1[j];
    for (int k = 0; k < HD; ++k) z = fmaf(emb[g * HD + k], Wh1[k * HD + j], z);
    for (int k = 0; k < NMETA; ++k) z = fmaf(meta[g * NMETA + k], Wh1[(HD + k) * HD + j], z);
    z = relu(z);
    __shared__ float red[128];
    red[j] = z * Wh2[j];
    __syncthreads();
    for (int s = 64; s > 0; s >>= 1) {
        if (j < s) red[j] += red[j + s];
        __syncthreads();
    }
    if (j == 0) out[g] = red[0] + bh2[0];
}

extern "C" void kernel_launch(void* const* d_in, const int* in_sizes, int n_in,
                              void* d_out, int out_size, void* d_ws, size_t ws_size,
                              hipStream_t stream) {
    const float* x     = (const float*)d_in[0];
    const int*   ei    = (const int*)d_in[1];
    const int*   src   = ei;
    const int*   dst   = ei + NE;
    const int*   batch = (const int*)d_in[2];
    const float* meta  = (const float*)d_in[3];
    const float* W1 = (const float*)d_in[4];  const float* b1 = (const float*)d_in[5];
    const float* W2 = (const float*)d_in[6];  const float* b2 = (const float*)d_in[7];
    const float* W3 = (const float*)d_in[8];  const float* b3 = (const float*)d_in[9];
    const float* Wh1 = (const float*)d_in[10]; const float* bh1 = (const float*)d_in[11];
    const float* Wh2 = (const float*)d_in[12]; const float* bh2 = (const float*)d_in[13];
    float* out = (float*)d_out;

    // workspace layout (16B-aligned sections)
    int2*  csr_sw   = (int2*)d_ws;                        // NE*8B
    int*   cnt      = (int*)(csr_sw + NE);                // NN
    int*   partial  = cnt + NN;                           // NN
    int*   blocksum = partial + NN;                       // 256
    int*   blockoff = blocksum + 256;                     // 256
    int*   rowptr   = blockoff + 256;                     // NN+1 (pad 8)
    int*   cursor   = rowptr + NN + 8;                    // NN
    float* dinv     = (float*)(cursor + NN);              // NN
    float* emb      = dinv + NN;                          // NB*HD f32
    unsigned short* Ta  = (unsigned short*)(emb + NB * HD);   // NN*HD bf16
    unsigned short* Tc  = Ta + (size_t)NN * HD;               // NN*HD bf16
    unsigned short* Hb  = Tc + (size_t)NN * HD;               // NN*HD bf16
    unsigned short* Wt1 = Hb + (size_t)NN * HD;               // HD*HD bf16
    unsigned short* Wt2 = Wt1 + HD * HD;
    unsigned short* Wt3 = Wt2 + HD * HD;

    const int GEMM_GRID  = (NN + 63) / 64;                // 782
    const int FUSED_GRID = NN / 16;                       // 3125 (exact)
    const int GATH_GRID  = (NN * 32 + 255) / 256;         // 6250
    const int CWT_GRID   = (3 * HD * HD + 255) / 256;     // 192

    // build CSR-by-dst
    hipMemsetAsync(cnt, 0, NN * sizeof(int), stream);
    k_count<<<(NE + 255) / 256, 256, 0, stream>>>(dst, cnt);
    k_scanA<<<SCAN_BLOCKS, 256, 0, stream>>>(cnt, partial, blocksum, dinv);
    k_scanB<<<1, 256, 0, stream>>>(blocksum, blockoff);
    k_scanC<<<SCAN_BLOCKS, 256, 0, stream>>>(partial, blockoff, rowptr, cursor);
    k_fill<<<(NE + 255) / 256, 256, 0, stream>>>(src, dst, dinv, cursor, csr_sw);

    k_castWt3<<<CWT_GRID, 256, 0, stream>>>(W1, W2, W3, Wt1, Wt2, Wt3);

    // layer 1: T1 = cast(x) @ W1
    k_gemm_x<<<GEMM_GRID, 256, 0, stream>>>(x, Wt1, Ta);
    // layer 1 gather + layer 2 gemm (H1 ephemeral in LDS): T2
    k_fused<<<FUSED_GRID, 512, 0, stream>>>(rowptr, csr_sw, Ta, dinv, b1, Wt2, Tc);
    // layer 2 gather + layer 3 gemm (H2 ephemeral): T3
    k_fused<<<FUSED_GRID, 512, 0, stream>>>(rowptr, csr_sw, Tc, dinv, b2, Wt3, Ta);
    // layer 3 gather -> H3 global
    k_gather<<<GATH_GRID, 256, 0, stream>>>(rowptr, csr_sw, Ta, dinv, b3, Hb);

    // pool + head
    k_pool<<<NB, 128, 0, stream>>>(Hb, batch, emb);
    k_head<<<NB, 128, 0, stream>>>(emb, meta, Wh1, bh1, Wh2, bh2, out);
}

// Round 8
// 322.371 us; speedup vs baseline: 10.4475x; 1.0454x over previous
//
#include <hip/hip_runtime.h>

#define NN 50000
#define NE 600000
#define NB 512
#define HD 128
#define NMETA 27
#define SCAN_BLOCKS ((NN + 255) / 256)   // 196

typedef __attribute__((ext_vector_type(8))) short short8;   // 8 bf16 (A/B frag)
typedef __attribute__((ext_vector_type(4))) float f32x4;    // C/D frag

__device__ __forceinline__ float relu(float x) { return fmaxf(x, 0.0f); }

// fp32 -> bf16 round-to-nearest-even
__device__ __forceinline__ unsigned short f2bf(float f) {
    unsigned u = __float_as_uint(f);
    unsigned r = u + 0x7FFFu + ((u >> 16) & 1u);
    return (unsigned short)(r >> 16);
}
__device__ __forceinline__ float bf2f(unsigned short v) {
    return __uint_as_float(((unsigned)v) << 16);
}

// ---------------- CSR build ----------------
__global__ __launch_bounds__(256) void k_count(const int* __restrict__ dst, int* __restrict__ cnt) {
    int i = blockIdx.x * 256 + threadIdx.x;
    if (i < NE) atomicAdd(&cnt[dst[i]], 1);
}

__global__ __launch_bounds__(256) void k_scanA(const int* __restrict__ cnt, int* __restrict__ partial,
                                               int* __restrict__ blocksum, float* __restrict__ dinv) {
    const int t = threadIdx.x;
    const int i = blockIdx.x * 256 + t;
    int v = (i < NN) ? cnt[i] : 0;
    if (i < NN) dinv[i] = rsqrtf((float)v + 1.0f);
    __shared__ int s[256];
    s[t] = v;
    __syncthreads();
    for (int off = 1; off < 256; off <<= 1) {
        int u = (t >= off) ? s[t - off] : 0;
        __syncthreads();
        s[t] += u;
        __syncthreads();
    }
    if (i < NN) partial[i] = s[t] - v;
    if (t == 255) blocksum[blockIdx.x] = s[255];
}

__global__ __launch_bounds__(256) void k_scanB(const int* __restrict__ blocksum, int* __restrict__ blockoff) {
    const int t = threadIdx.x;
    int v = (t < SCAN_BLOCKS) ? blocksum[t] : 0;
    __shared__ int s[256];
    s[t] = v;
    __syncthreads();
    for (int off = 1; off < 256; off <<= 1) {
        int u = (t >= off) ? s[t - off] : 0;
        __syncthreads();
        s[t] += u;
        __syncthreads();
    }
    if (t < SCAN_BLOCKS) blockoff[t] = s[t] - v;
}

__global__ __launch_bounds__(256) void k_scanC(const int* __restrict__ partial, const int* __restrict__ blockoff,
                                               int* __restrict__ rowptr, int* __restrict__ cursor) {
    const int i = blockIdx.x * 256 + threadIdx.x;
    if (i < NN) {
        int rp = partial[i] + blockoff[i >> 8];
        rowptr[i] = rp;
        cursor[i] = rp;
    }
    if (i == 0) rowptr[NN] = NE;
}

__global__ __launch_bounds__(256) void k_fill(const int* __restrict__ src, const int* __restrict__ dst,
                                              const float* __restrict__ dinv, int* __restrict__ cursor,
                                              int2* __restrict__ csr_sw) {
    int e = blockIdx.x * 256 + threadIdx.x;
    if (e >= NE) return;
    int s = src[e], d = dst[e];
    int pos = atomicAdd(&cursor[d], 1);
    csr_sw[pos] = make_int2(s, __float_as_int(dinv[s] * dinv[d]));
}

// all three W [128][128] f32 row-major (k,n) -> Wt bf16 [n][k], one launch
__global__ __launch_bounds__(256) void k_castWt3(const float* __restrict__ W1, const float* __restrict__ W2,
                                                 const float* __restrict__ W3, unsigned short* __restrict__ Wt1,
                                                 unsigned short* __restrict__ Wt2, unsigned short* __restrict__ Wt3) {
    int i = blockIdx.x * 256 + threadIdx.x;
    if (i >= 3 * HD * HD) return;
    int which = i / (HD * HD);
    int r = i - which * (HD * HD);
    int k = r >> 7, n = r & 127;
    const float* W = (which == 0) ? W1 : (which == 1) ? W2 : W3;
    unsigned short* Wt = (which == 0) ? Wt1 : (which == 1) ? Wt2 : Wt3;
    Wt[n * HD + k] = f2bf(W[r]);
}

// ---------------- layer-1 GEMM: T1 = cast(x) @ W1, x fp32 read directly ----------------
__global__ __launch_bounds__(256) void k_gemm_x(const float* __restrict__ X,
                                                const unsigned short* __restrict__ Wt,
                                                unsigned short* __restrict__ T) {
    __shared__ unsigned short Ws[HD * HD];      // 32 KB
    char* wsb = (char*)Ws;
    for (int i = threadIdx.x; i < HD * HD / 8; i += 256) {
        short8 v = ((const short8*)Wt)[i];
        int byte = i * 16;
        *(short8*)(wsb + (byte ^ (((byte >> 8) & 7) << 4))) = v;
    }
    __syncthreads();

    const int wave = threadIdx.x >> 6;
    const int lane = threadIdx.x & 63;
    const int lr = lane & 15;
    const int kh = lane >> 4;
    const int r0 = blockIdx.x * 64 + wave * 16;
    const float* arow = X + (size_t)min(r0 + lr, NN - 1) * HD + kh * 8;

    f32x4 acc[8] = {};
#pragma unroll
    for (int kk = 0; kk < 4; ++kk) {
        float4 a0 = *reinterpret_cast<const float4*>(arow + kk * 32);
        float4 a1 = *reinterpret_cast<const float4*>(arow + kk * 32 + 4);
        short8 af;
        af[0] = (short)f2bf(a0.x); af[1] = (short)f2bf(a0.y);
        af[2] = (short)f2bf(a0.z); af[3] = (short)f2bf(a0.w);
        af[4] = (short)f2bf(a1.x); af[5] = (short)f2bf(a1.y);
        af[6] = (short)f2bf(a1.z); af[7] = (short)f2bf(a1.w);
#pragma unroll
        for (int n = 0; n < 8; ++n) {
            int byte = (n * 16 + lr) * 256 + kk * 64 + kh * 16;
            short8 bf = *(const short8*)(wsb + (byte ^ (((byte >> 8) & 7) << 4)));
            acc[n] = __builtin_amdgcn_mfma_f32_16x16x32_bf16(af, bf, acc[n], 0, 0, 0);
        }
    }
#pragma unroll
    for (int n = 0; n < 8; ++n) {
#pragma unroll
        for (int r = 0; r < 4; ++r) {
            int row = r0 + kh * 4 + r;
            if (row < NN) T[(size_t)row * HD + n * 16 + lr] = f2bf(acc[n][r]);
        }
    }
}

// ---------------- fused gather -> (optional GEMM) ----------------
// 512 thr = 8 waves, 32 rows/block, grid = ceil(NN/32) = 1563.
// Phase 1: 16 lanes/row, each lane 2 column-quads (c0 in [0,64), c1 in [64,128)).
//   4-edge unroll, two-deep int2 software pipeline -> 8 independent row-gathers
//   + 4 prefetched edge records in flight per lane.
// Phase 2 (DO_GEMM=1): 2 row-tiles x 8 col-tiles; wave w does col-tile w for
//   both halves, B-fragment loaded once per kk and reused.
template <int DO_GEMM>
__global__ __launch_bounds__(512, 8) void k_fused(const int* __restrict__ rowptr, const int2* __restrict__ csr_sw,
                                                  const unsigned short* __restrict__ Tin, const float* __restrict__ dinv,
                                                  const float* __restrict__ b, const unsigned short* __restrict__ Wt,
                                                  unsigned short* __restrict__ Out) {
    __shared__ unsigned short Hs[32 * HD];      // 8 KB
    char* hsb = (char*)Hs;

    const int rl  = threadIdx.x >> 4;           // 0..31 row within tile
    const int l16 = threadIdx.x & 15;
    const int row = blockIdx.x * 32 + rl;
    const int c0  = l16 * 4;
    const int c1  = 64 + l16 * 4;

    float a0x = 0.f, a0y = 0.f, a0z = 0.f, a0w = 0.f;
    float a1x = 0.f, a1y = 0.f, a1z = 0.f, a1w = 0.f;

    if (row < NN) {
        const int lo = rowptr[row], hi = rowptr[row + 1];
        int j = lo;
        int2 sA0, sA1, sA2, sA3, sB0, sB1, sB2, sB3;
        bool haveA = (j + 3 < hi);
        if (haveA) { sA0 = csr_sw[j]; sA1 = csr_sw[j + 1]; sA2 = csr_sw[j + 2]; sA3 = csr_sw[j + 3]; }
        while (haveA) {
            const int jn = j + 4;
            const bool haveB = (jn + 3 < hi);
            if (haveB) { sB0 = csr_sw[jn]; sB1 = csr_sw[jn + 1]; sB2 = csr_sw[jn + 2]; sB3 = csr_sw[jn + 3]; }
            const unsigned short* r0 = Tin + (size_t)sA0.x * HD;
            const unsigned short* r1 = Tin + (size_t)sA1.x * HD;
            const unsigned short* r2 = Tin + (size_t)sA2.x * HD;
            const unsigned short* r3 = Tin + (size_t)sA3.x * HD;
            ushort4 p00 = *reinterpret_cast<const ushort4*>(r0 + c0);
            ushort4 p01 = *reinterpret_cast<const ushort4*>(r0 + c1);
            ushort4 p10 = *reinterpret_cast<const ushort4*>(r1 + c0);
            ushort4 p11 = *reinterpret_cast<const ushort4*>(r1 + c1);
            ushort4 p20 = *reinterpret_cast<const ushort4*>(r2 + c0);
            ushort4 p21 = *reinterpret_cast<const ushort4*>(r2 + c1);
            ushort4 p30 = *reinterpret_cast<const ushort4*>(r3 + c0);
            ushort4 p31 = *reinterpret_cast<const ushort4*>(r3 + c1);
            float w0 = __int_as_float(sA0.y), w1 = __int_as_float(sA1.y);
            float w2 = __int_as_float(sA2.y), w3 = __int_as_float(sA3.y);
            a0x = fmaf(bf2f(p00.x), w0, a0x); a0y = fmaf(bf2f(p00.y), w0, a0y);
            a0z = fmaf(bf2f(p00.z), w0, a0z); a0w = fmaf(bf2f(p00.w), w0, a0w);
            a1x = fmaf(bf2f(p01.x), w0, a1x); a1y = fmaf(bf2f(p01.y), w0, a1y);
            a1z = fmaf(bf2f(p01.z), w0, a1z); a1w = fmaf(bf2f(p01.w), w0, a1w);
            a0x = fmaf(bf2f(p10.x), w1, a0x); a0y = fmaf(bf2f(p10.y), w1, a0y);
            a0z = fmaf(bf2f(p10.z), w1, a0z); a0w = fmaf(bf2f(p10.w), w1, a0w);
            a1x = fmaf(bf2f(p11.x), w1, a1x); a1y = fmaf(bf2f(p11.y), w1, a1y);
            a1z = fmaf(bf2f(p11.z), w1, a1z); a1w = fmaf(bf2f(p11.w), w1, a1w);
            a0x = fmaf(bf2f(p20.x), w2, a0x); a0y = fmaf(bf2f(p20.y), w2, a0y);
            a0z = fmaf(bf2f(p20.z), w2, a0z); a0w = fmaf(bf2f(p20.w), w2, a0w);
            a1x = fmaf(bf2f(p21.x), w2, a1x); a1y = fmaf(bf2f(p21.y), w2, a1y);
            a1z = fmaf(bf2f(p21.z), w2, a1z); a1w = fmaf(bf2f(p21.w), w2, a1w);
            a0x = fmaf(bf2f(p30.x), w3, a0x); a0y = fmaf(bf2f(p30.y), w3, a0y);
            a0z = fmaf(bf2f(p30.z), w3, a0z); a0w = fmaf(bf2f(p30.w), w3, a0w);
            a1x = fmaf(bf2f(p31.x), w3, a1x); a1y = fmaf(bf2f(p31.y), w3, a1y);
            a1z = fmaf(bf2f(p31.z), w3, a1z); a1w = fmaf(bf2f(p31.w), w3, a1w);
            j = jn;
            sA0 = sB0; sA1 = sB1; sA2 = sB2; sA3 = sB3;
            haveA = haveB;
        }
        for (; j < hi; ++j) {
            int2 sw = csr_sw[j];
            float w = __int_as_float(sw.y);
            const unsigned short* rr = Tin + (size_t)sw.x * HD;
            ushort4 t0 = *reinterpret_cast<const ushort4*>(rr + c0);
            ushort4 t1 = *reinterpret_cast<const ushort4*>(rr + c1);
            a0x = fmaf(bf2f(t0.x), w, a0x); a0y = fmaf(bf2f(t0.y), w, a0y);
            a0z = fmaf(bf2f(t0.z), w, a0z); a0w = fmaf(bf2f(t0.w), w, a0w);
            a1x = fmaf(bf2f(t1.x), w, a1x); a1y = fmaf(bf2f(t1.y), w, a1y);
            a1z = fmaf(bf2f(t1.z), w, a1z); a1w = fmaf(bf2f(t1.w), w, a1w);
        }
        const float di = dinv[row];
        const float sl = di * di;
        ushort4 ts0 = *reinterpret_cast<const ushort4*>(Tin + (size_t)row * HD + c0);
        ushort4 ts1 = *reinterpret_cast<const ushort4*>(Tin + (size_t)row * HD + c1);
        float4 bb0 = *reinterpret_cast<const float4*>(b + c0);
        float4 bb1 = *reinterpret_cast<const float4*>(b + c1);
        ushort4 o0, o1;
        o0.x = f2bf(relu(fmaf(bf2f(ts0.x), sl, a0x) + bb0.x));
        o0.y = f2bf(relu(fmaf(bf2f(ts0.y), sl, a0y) + bb0.y));
        o0.z = f2bf(relu(fmaf(bf2f(ts0.z), sl, a0z) + bb0.z));
        o0.w = f2bf(relu(fmaf(bf2f(ts0.w), sl, a0w) + bb0.w));
        o1.x = f2bf(relu(fmaf(bf2f(ts1.x), sl, a1x) + bb1.x));
        o1.y = f2bf(relu(fmaf(bf2f(ts1.y), sl, a1y) + bb1.y));
        o1.z = f2bf(relu(fmaf(bf2f(ts1.z), sl, a1z) + bb1.z));
        o1.w = f2bf(relu(fmaf(bf2f(ts1.w), sl, a1w) + bb1.w));
        if (DO_GEMM) {
            int byte0 = rl * 256 + c0 * 2;
            int byte1 = rl * 256 + c1 * 2;
            *(ushort4*)(hsb + (byte0 ^ (((byte0 >> 8) & 7) << 4))) = o0;
            *(ushort4*)(hsb + (byte1 ^ (((byte1 >> 8) & 7) << 4))) = o1;
        } else {
            *reinterpret_cast<ushort4*>(Out + (size_t)row * HD + c0) = o0;
            *reinterpret_cast<ushort4*>(Out + (size_t)row * HD + c1) = o1;
        }
    } else if (DO_GEMM) {
        ushort4 z = {0, 0, 0, 0};
        int byte0 = rl * 256 + c0 * 2;
        int byte1 = rl * 256 + c1 * 2;
        *(ushort4*)(hsb + (byte0 ^ (((byte0 >> 8) & 7) << 4))) = z;
        *(ushort4*)(hsb + (byte1 ^ (((byte1 >> 8) & 7) << 4))) = z;
    }

    if (DO_GEMM) {
        __syncthreads();
        const int w = threadIdx.x >> 6;       // col-tile 0..7
        const int lane = threadIdx.x & 63;
        const int lr = lane & 15;
        const int kh = lane >> 4;
        f32x4 acc0 = {}, acc1 = {};
#pragma unroll
        for (int kk = 0; kk < 4; ++kk) {
            short8 bf = *reinterpret_cast<const short8*>(Wt + (size_t)(w * 16 + lr) * HD + kk * 32 + kh * 8);
            int byteA = lr * 256 + kk * 64 + kh * 16;
            int byteB = (16 + lr) * 256 + kk * 64 + kh * 16;
            short8 af0 = *(const short8*)(hsb + (byteA ^ (((byteA >> 8) & 7) << 4)));
            short8 af1 = *(const short8*)(hsb + (byteB ^ (((byteB >> 8) & 7) << 4)));
            acc0 = __builtin_amdgcn_mfma_f32_16x16x32_bf16(af0, bf, acc0, 0, 0, 0);
            acc1 = __builtin_amdgcn_mfma_f32_16x16x32_bf16(af1, bf, acc1, 0, 0, 0);
        }
#pragma unroll
        for (int r = 0; r < 4; ++r) {
            int row0 = blockIdx.x * 32 + kh * 4 + r;
            int row1 = row0 + 16;
            if (row0 < NN) Out[(size_t)row0 * HD + w * 16 + lr] = f2bf(acc0[r]);
            if (row1 < NN) Out[(size_t)row1 * HD + w * 16 + lr] = f2bf(acc1[r]);
        }
    }
}

// ---------------- fused mean-pool + head (emb in LDS) ----------------
__global__ __launch_bounds__(128) void k_poolhead(const unsigned short* __restrict__ H, const int* __restrict__ batch,
                                                  const float* __restrict__ meta,
                                                  const float* __restrict__ Wh1, const float* __restrict__ bh1,
                                                  const float* __restrict__ Wh2, const float* __restrict__ bh2,
                                                  float* __restrict__ out) {
    int g = blockIdx.x;
    int l = 0, r = NN;
    while (l < r) { int m = (l + r) >> 1; if (batch[m] < g) l = m + 1; else r = m; }
    int lo = l;
    r = NN;
    while (l < r) { int m = (l + r) >> 1; if (batch[m] < g + 1) l = m + 1; else r = m; }
    int hi = l;
    int c = threadIdx.x;
    float s = 0.0f;
    for (int i = lo; i < hi; ++i) s += bf2f(H[(size_t)i * HD + c]);
    float cnt = (float)max(hi - lo, 1);
    __shared__ float emb[128];
    emb[c] = s / cnt;
    __syncthreads();
    float z = bh1[c];
    for (int k = 0; k < HD; ++k) z = fmaf(emb[k], Wh1[k * HD + c], z);
    for (int k = 0; k < NMETA; ++k) z = fmaf(meta[g * NMETA + k], Wh1[(HD + k) * HD + c], z);
    z = relu(z);
    __shared__ float red[128];
    red[c] = z * Wh2[c];
    __syncthreads();
    for (int st = 64; st > 0; st >>= 1) {
        if (c < st) red[c] += red[c + st];
        __syncthreads();
    }
    if (c == 0) out[g] = red[0] + bh2[0];
}

extern "C" void kernel_launch(void* const* d_in, const int* in_sizes, int n_in,
                              void* d_out, int out_size, void* d_ws, size_t ws_size,
                              hipStream_t stream) {
    const float* x     = (const float*)d_in[0];
    const int*   ei    = (const int*)d_in[1];
    const int*   src   = ei;
    const int*   dst   = ei + NE;
    const int*   batch = (const int*)d_in[2];
    const float* meta  = (const float*)d_in[3];
    const float* W1 = (const float*)d_in[4];  const float* b1 = (const float*)d_in[5];
    const float* W2 = (const float*)d_in[6];  const float* b2 = (const float*)d_in[7];
    const float* W3 = (const float*)d_in[8];  const float* b3 = (const float*)d_in[9];
    const float* Wh1 = (const float*)d_in[10]; const float* bh1 = (const float*)d_in[11];
    const float* Wh2 = (const float*)d_in[12]; const float* bh2 = (const float*)d_in[13];
    float* out = (float*)d_out;

    // workspace layout (16B-aligned sections)
    int2*  csr_sw   = (int2*)d_ws;                        // NE*8B
    int*   cnt      = (int*)(csr_sw + NE);                // NN
    int*   partial  = cnt + NN;                           // NN
    int*   blocksum = partial + NN;                       // 256
    int*   blockoff = blocksum + 256;                     // 256
    int*   rowptr   = blockoff + 256;                     // NN+1 (pad 8)
    int*   cursor   = rowptr + NN + 8;                    // NN
    float* dinv     = (float*)(cursor + NN);              // NN
    unsigned short* Ta  = (unsigned short*)(dinv + NN);       // NN*HD bf16
    unsigned short* Tc  = Ta + (size_t)NN * HD;               // NN*HD bf16
    unsigned short* Hb  = Tc + (size_t)NN * HD;               // NN*HD bf16
    unsigned short* Wt1 = Hb + (size_t)NN * HD;               // HD*HD bf16
    unsigned short* Wt2 = Wt1 + HD * HD;
    unsigned short* Wt3 = Wt2 + HD * HD;

    const int GEMM_GRID  = (NN + 63) / 64;                // 782
    const int FUSED_GRID = (NN + 31) / 32;                // 1563
    const int CWT_GRID   = (3 * HD * HD + 255) / 256;     // 192

    // build CSR-by-dst
    hipMemsetAsync(cnt, 0, NN * sizeof(int), stream);
    k_count<<<(NE + 255) / 256, 256, 0, stream>>>(dst, cnt);
    k_scanA<<<SCAN_BLOCKS, 256, 0, stream>>>(cnt, partial, blocksum, dinv);
    k_scanB<<<1, 256, 0, stream>>>(blocksum, blockoff);
    k_scanC<<<SCAN_BLOCKS, 256, 0, stream>>>(partial, blockoff, rowptr, cursor);
    k_fill<<<(NE + 255) / 256, 256, 0, stream>>>(src, dst, dinv, cursor, csr_sw);

    k_castWt3<<<CWT_GRID, 256, 0, stream>>>(W1, W2, W3, Wt1, Wt2, Wt3);

    // layer 1: T1 = cast(x) @ W1
    k_gemm_x<<<GEMM_GRID, 256, 0, stream>>>(x, Wt1, Ta);
    // layer 1 gather + layer 2 gemm (H1 ephemeral in LDS): T2
    k_fused<1><<<FUSED_GRID, 512, 0, stream>>>(rowptr, csr_sw, Ta, dinv, b1, Wt2, Tc);
    // layer 2 gather + layer 3 gemm (H2 ephemeral): T3
    k_fused<1><<<FUSED_GRID, 512, 0, stream>>>(rowptr, csr_sw, Tc, dinv, b2, Wt3, Ta);
    // layer 3 gather -> H3 global (no GEMM)
    k_fused<0><<<FUSED_GRID, 512, 0, stream>>>(rowptr, csr_sw, Ta, dinv, b3, (const unsigned short*)nullptr, Hb);

    // pool + head fused
    k_poolhead<<<NB, 128, 0, stream>>>(Hb, batch, meta, Wh1, bh1, Wh2, bh2, out);
}

// Round 9
// 299.900 us; speedup vs baseline: 11.2303x; 1.0749x over previous
//
#include <hip/hip_runtime.h>

#define NN 50000
#define NE 600000
#define NB 512
#define HD 128
#define NMETA 27
#define SCAN_BLOCKS ((NN + 255) / 256)   // 196

typedef __attribute__((ext_vector_type(8))) short short8;   // 8 bf16 (A/B frag)
typedef __attribute__((ext_vector_type(4))) float f32x4;    // C/D frag

__device__ __forceinline__ float relu(float x) { return fmaxf(x, 0.0f); }

// fp32 -> bf16 round-to-nearest-even
__device__ __forceinline__ unsigned short f2bf(float f) {
    unsigned u = __float_as_uint(f);
    unsigned r = u + 0x7FFFu + ((u >> 16) & 1u);
    return (unsigned short)(r >> 16);
}
__device__ __forceinline__ float bf2f(unsigned short v) {
    return __uint_as_float(((unsigned)v) << 16);
}

// ---------------- CSR build ----------------
__global__ __launch_bounds__(256) void k_count(const int* __restrict__ dst, int* __restrict__ cnt) {
    int i = blockIdx.x * 256 + threadIdx.x;
    if (i < NE) atomicAdd(&cnt[dst[i]], 1);
}

__global__ __launch_bounds__(256) void k_scanA(const int* __restrict__ cnt, int* __restrict__ partial,
                                               int* __restrict__ blocksum, float* __restrict__ dinv) {
    const int t = threadIdx.x;
    const int i = blockIdx.x * 256 + t;
    int v = (i < NN) ? cnt[i] : 0;
    if (i < NN) dinv[i] = rsqrtf((float)v + 1.0f);
    __shared__ int s[256];
    s[t] = v;
    __syncthreads();
    for (int off = 1; off < 256; off <<= 1) {
        int u = (t >= off) ? s[t - off] : 0;
        __syncthreads();
        s[t] += u;
        __syncthreads();
    }
    if (i < NN) partial[i] = s[t] - v;
    if (t == 255) blocksum[blockIdx.x] = s[255];
}

__global__ __launch_bounds__(256) void k_scanB(const int* __restrict__ blocksum, int* __restrict__ blockoff) {
    const int t = threadIdx.x;
    int v = (t < SCAN_BLOCKS) ? blocksum[t] : 0;
    __shared__ int s[256];
    s[t] = v;
    __syncthreads();
    for (int off = 1; off < 256; off <<= 1) {
        int u = (t >= off) ? s[t - off] : 0;
        __syncthreads();
        s[t] += u;
        __syncthreads();
    }
    if (t < SCAN_BLOCKS) blockoff[t] = s[t] - v;
}

__global__ __launch_bounds__(256) void k_scanC(const int* __restrict__ partial, const int* __restrict__ blockoff,
                                               int* __restrict__ rowptr, int* __restrict__ cursor) {
    const int i = blockIdx.x * 256 + threadIdx.x;
    if (i < NN) {
        int rp = partial[i] + blockoff[i >> 8];
        rowptr[i] = rp;
        cursor[i] = rp;
    }
    if (i == 0) rowptr[NN] = NE;
}

// fill CSR: src index only (norm factored into T' producer-side)
__global__ __launch_bounds__(256) void k_fill(const int* __restrict__ src, const int* __restrict__ dst,
                                              int* __restrict__ cursor, int* __restrict__ csr_src) {
    int e = blockIdx.x * 256 + threadIdx.x;
    if (e >= NE) return;
    int s = src[e], d = dst[e];
    int pos = atomicAdd(&cursor[d], 1);
    csr_src[pos] = s;
}

// all three W [128][128] f32 row-major (k,n) -> Wt bf16 [n][k], one launch
__global__ __launch_bounds__(256) void k_castWt3(const float* __restrict__ W1, const float* __restrict__ W2,
                                                 const float* __restrict__ W3, unsigned short* __restrict__ Wt1,
                                                 unsigned short* __restrict__ Wt2, unsigned short* __restrict__ Wt3) {
    int i = blockIdx.x * 256 + threadIdx.x;
    if (i >= 3 * HD * HD) return;
    int which = i / (HD * HD);
    int r = i - which * (HD * HD);
    int k = r >> 7, n = r & 127;
    const float* W = (which == 0) ? W1 : (which == 1) ? W2 : W3;
    unsigned short* Wt = (which == 0) ? Wt1 : (which == 1) ? Wt2 : Wt3;
    Wt[n * HD + k] = f2bf(W[r]);
}

// ---------------- layer-1 GEMM: T1' = (cast(x) @ W1) * dinv[row] ----------------
__global__ __launch_bounds__(256) void k_gemm_x(const float* __restrict__ X,
                                                const unsigned short* __restrict__ Wt,
                                                const float* __restrict__ dinv,
                                                unsigned short* __restrict__ T) {
    __shared__ unsigned short Ws[HD * HD];      // 32 KB
    char* wsb = (char*)Ws;
    for (int i = threadIdx.x; i < HD * HD / 8; i += 256) {
        short8 v = ((const short8*)Wt)[i];
        int byte = i * 16;
        *(short8*)(wsb + (byte ^ (((byte >> 8) & 7) << 4))) = v;
    }
    __syncthreads();

    const int wave = threadIdx.x >> 6;
    const int lane = threadIdx.x & 63;
    const int lr = lane & 15;
    const int kh = lane >> 4;
    const int r0 = blockIdx.x * 64 + wave * 16;
    const float* arow = X + (size_t)min(r0 + lr, NN - 1) * HD + kh * 8;

    f32x4 acc[8] = {};
#pragma unroll
    for (int kk = 0; kk < 4; ++kk) {
        float4 a0 = *reinterpret_cast<const float4*>(arow + kk * 32);
        float4 a1 = *reinterpret_cast<const float4*>(arow + kk * 32 + 4);
        short8 af;
        af[0] = (short)f2bf(a0.x); af[1] = (short)f2bf(a0.y);
        af[2] = (short)f2bf(a0.z); af[3] = (short)f2bf(a0.w);
        af[4] = (short)f2bf(a1.x); af[5] = (short)f2bf(a1.y);
        af[6] = (short)f2bf(a1.z); af[7] = (short)f2bf(a1.w);
#pragma unroll
        for (int n = 0; n < 8; ++n) {
            int byte = (n * 16 + lr) * 256 + kk * 64 + kh * 16;
            short8 bf = *(const short8*)(wsb + (byte ^ (((byte >> 8) & 7) << 4)));
            acc[n] = __builtin_amdgcn_mfma_f32_16x16x32_bf16(af, bf, acc[n], 0, 0, 0);
        }
    }
    float dv[4];
#pragma unroll
    for (int r = 0; r < 4; ++r) {
        int row = r0 + kh * 4 + r;
        dv[r] = (row < NN) ? dinv[row] : 0.0f;
    }
#pragma unroll
    for (int n = 0; n < 8; ++n) {
#pragma unroll
        for (int r = 0; r < 4; ++r) {
            int row = r0 + kh * 4 + r;
            if (row < NN) T[(size_t)row * HD + n * 16 + lr] = f2bf(acc[n][r] * dv[r]);
        }
    }
}

// ---------------- fused gather -> {GEMM | POOL} ----------------
// 512 thr = 8 waves, 32 rows/block, grid = ceil(NN/32) = 1563.
// Gather: H[row] = relu( dinv[row]*(sum_e T'[src_e] + T'[row]) + b ), T' pre-scaled.
// MODE 1: H (bf16, swizzled LDS) -> T_out' = (H @ Wt)*dinv  (2 row-tiles x 8 col-tiles)
// MODE 2: H (fp32, padded LDS) -> sorted-batch segment-reduce -> atomicAdd embsum
template <int MODE>
__global__ __launch_bounds__(512, 8) void k_fused(const int* __restrict__ rowptr, const int* __restrict__ csr_src,
                                                  const unsigned short* __restrict__ Tin, const float* __restrict__ dinv,
                                                  const float* __restrict__ b, const unsigned short* __restrict__ Wt,
                                                  unsigned short* __restrict__ Out, const int* __restrict__ batch,
                                                  float* __restrict__ embsum) {
    __shared__ char smem[32 * 132 * 4 + 128];   // fp32 padded tile + sg[32]
    char* hsb = smem;                            // MODE1: bf16 swizzled in first 8KB
    float* hsf = (float*)smem;                   // MODE2: [32][132] fp32
    int* sg = (int*)(smem + 32 * 132 * 4);

    const int rl  = threadIdx.x >> 4;           // 0..31 row within tile
    const int l16 = threadIdx.x & 15;
    const int row = blockIdx.x * 32 + rl;
    const int c0  = l16 * 4;
    const int c1  = 64 + l16 * 4;

    if (MODE == 2 && threadIdx.x < 32) {
        int rr = blockIdx.x * 32 + threadIdx.x;
        sg[threadIdx.x] = (rr < NN) ? batch[rr] : -1;
    }

    float a0x = 0.f, a0y = 0.f, a0z = 0.f, a0w = 0.f;
    float a1x = 0.f, a1y = 0.f, a1z = 0.f, a1w = 0.f;

    if (row < NN) {
        const int lo = rowptr[row], hi = rowptr[row + 1];
        int j = lo;
        int sA0, sA1, sA2, sA3, sB0, sB1, sB2, sB3;
        bool haveA = (j + 3 < hi);
        if (haveA) { sA0 = csr_src[j]; sA1 = csr_src[j + 1]; sA2 = csr_src[j + 2]; sA3 = csr_src[j + 3]; }
        while (haveA) {
            const int jn = j + 4;
            const bool haveB = (jn + 3 < hi);
            if (haveB) { sB0 = csr_src[jn]; sB1 = csr_src[jn + 1]; sB2 = csr_src[jn + 2]; sB3 = csr_src[jn + 3]; }
            const unsigned short* r0 = Tin + (size_t)sA0 * HD;
            const unsigned short* r1 = Tin + (size_t)sA1 * HD;
            const unsigned short* r2 = Tin + (size_t)sA2 * HD;
            const unsigned short* r3 = Tin + (size_t)sA3 * HD;
            ushort4 p00 = *reinterpret_cast<const ushort4*>(r0 + c0);
            ushort4 p01 = *reinterpret_cast<const ushort4*>(r0 + c1);
            ushort4 p10 = *reinterpret_cast<const ushort4*>(r1 + c0);
            ushort4 p11 = *reinterpret_cast<const ushort4*>(r1 + c1);
            ushort4 p20 = *reinterpret_cast<const ushort4*>(r2 + c0);
            ushort4 p21 = *reinterpret_cast<const ushort4*>(r2 + c1);
            ushort4 p30 = *reinterpret_cast<const ushort4*>(r3 + c0);
            ushort4 p31 = *reinterpret_cast<const ushort4*>(r3 + c1);
            a0x += bf2f(p00.x); a0y += bf2f(p00.y); a0z += bf2f(p00.z); a0w += bf2f(p00.w);
            a1x += bf2f(p01.x); a1y += bf2f(p01.y); a1z += bf2f(p01.z); a1w += bf2f(p01.w);
            a0x += bf2f(p10.x); a0y += bf2f(p10.y); a0z += bf2f(p10.z); a0w += bf2f(p10.w);
            a1x += bf2f(p11.x); a1y += bf2f(p11.y); a1z += bf2f(p11.z); a1w += bf2f(p11.w);
            a0x += bf2f(p20.x); a0y += bf2f(p20.y); a0z += bf2f(p20.z); a0w += bf2f(p20.w);
            a1x += bf2f(p21.x); a1y += bf2f(p21.y); a1z += bf2f(p21.z); a1w += bf2f(p21.w);
            a0x += bf2f(p30.x); a0y += bf2f(p30.y); a0z += bf2f(p30.z); a0w += bf2f(p30.w);
            a1x += bf2f(p31.x); a1y += bf2f(p31.y); a1z += bf2f(p31.z); a1w += bf2f(p31.w);
            j = jn;
            sA0 = sB0; sA1 = sB1; sA2 = sB2; sA3 = sB3;
            haveA = haveB;
        }
        for (; j < hi; ++j) {
            int s = csr_src[j];
            const unsigned short* rr = Tin + (size_t)s * HD;
            ushort4 t0 = *reinterpret_cast<const ushort4*>(rr + c0);
            ushort4 t1 = *reinterpret_cast<const ushort4*>(rr + c1);
            a0x += bf2f(t0.x); a0y += bf2f(t0.y); a0z += bf2f(t0.z); a0w += bf2f(t0.w);
            a1x += bf2f(t1.x); a1y += bf2f(t1.y); a1z += bf2f(t1.z); a1w += bf2f(t1.w);
        }
        const float di = dinv[row];
        ushort4 ts0 = *reinterpret_cast<const ushort4*>(Tin + (size_t)row * HD + c0);
        ushort4 ts1 = *reinterpret_cast<const ushort4*>(Tin + (size_t)row * HD + c1);
        float4 bb0 = *reinterpret_cast<const float4*>(b + c0);
        float4 bb1 = *reinterpret_cast<const float4*>(b + c1);
        float h0x = relu(fmaf(di, a0x + bf2f(ts0.x), bb0.x));
        float h0y = relu(fmaf(di, a0y + bf2f(ts0.y), bb0.y));
        float h0z = relu(fmaf(di, a0z + bf2f(ts0.z), bb0.z));
        float h0w = relu(fmaf(di, a0w + bf2f(ts0.w), bb0.w));
        float h1x = relu(fmaf(di, a1x + bf2f(ts1.x), bb1.x));
        float h1y = relu(fmaf(di, a1y + bf2f(ts1.y), bb1.y));
        float h1z = relu(fmaf(di, a1z + bf2f(ts1.z), bb1.z));
        float h1w = relu(fmaf(di, a1w + bf2f(ts1.w), bb1.w));
        if (MODE == 1) {
            ushort4 o0, o1;
            o0.x = f2bf(h0x); o0.y = f2bf(h0y); o0.z = f2bf(h0z); o0.w = f2bf(h0w);
            o1.x = f2bf(h1x); o1.y = f2bf(h1y); o1.z = f2bf(h1z); o1.w = f2bf(h1w);
            int byte0 = rl * 256 + c0 * 2;
            int byte1 = rl * 256 + c1 * 2;
            *(ushort4*)(hsb + (byte0 ^ (((byte0 >> 8) & 7) << 4))) = o0;
            *(ushort4*)(hsb + (byte1 ^ (((byte1 >> 8) & 7) << 4))) = o1;
        } else {
            *(float4*)(smem + (rl * 132 + c0) * 4) = make_float4(h0x, h0y, h0z, h0w);
            *(float4*)(smem + (rl * 132 + c1) * 4) = make_float4(h1x, h1y, h1z, h1w);
        }
    } else {
        if (MODE == 1) {
            ushort4 z = {0, 0, 0, 0};
            int byte0 = rl * 256 + c0 * 2;
            int byte1 = rl * 256 + c1 * 2;
            *(ushort4*)(hsb + (byte0 ^ (((byte0 >> 8) & 7) << 4))) = z;
            *(ushort4*)(hsb + (byte1 ^ (((byte1 >> 8) & 7) << 4))) = z;
        } else {
            float4 z = make_float4(0.f, 0.f, 0.f, 0.f);
            *(float4*)(smem + (rl * 132 + c0) * 4) = z;
            *(float4*)(smem + (rl * 132 + c1) * 4) = z;
        }
    }
    __syncthreads();

    if (MODE == 1) {
        // T_out' = (H @ Wt) * dinv
        const int w = threadIdx.x >> 6;       // col-tile 0..7
        const int lane = threadIdx.x & 63;
        const int lr = lane & 15;
        const int kh = lane >> 4;
        f32x4 acc0 = {}, acc1 = {};
#pragma unroll
        for (int kk = 0; kk < 4; ++kk) {
            short8 bf = *reinterpret_cast<const short8*>(Wt + (size_t)(w * 16 + lr) * HD + kk * 32 + kh * 8);
            int byteA = lr * 256 + kk * 64 + kh * 16;
            int byteB = (16 + lr) * 256 + kk * 64 + kh * 16;
            short8 af0 = *(const short8*)(hsb + (byteA ^ (((byteA >> 8) & 7) << 4)));
            short8 af1 = *(const short8*)(hsb + (byteB ^ (((byteB >> 8) & 7) << 4)));
            acc0 = __builtin_amdgcn_mfma_f32_16x16x32_bf16(af0, bf, acc0, 0, 0, 0);
            acc1 = __builtin_amdgcn_mfma_f32_16x16x32_bf16(af1, bf, acc1, 0, 0, 0);
        }
#pragma unroll
        for (int r = 0; r < 4; ++r) {
            int row0 = blockIdx.x * 32 + kh * 4 + r;
            int row1 = row0 + 16;
            if (row0 < NN) Out[(size_t)row0 * HD + w * 16 + lr] = f2bf(acc0[r] * dinv[row0]);
            if (row1 < NN) Out[(size_t)row1 * HD + w * 16 + lr] = f2bf(acc1[r] * dinv[row1]);
        }
    } else {
        // segment-reduce 32 sorted rows -> atomicAdd into embsum
        if (threadIdx.x < HD) {
            const int c = threadIdx.x;
            float acc = 0.f;
            int gcur = -1;
#pragma unroll 8
            for (int r = 0; r < 32; ++r) {
                int g = sg[r];
                if (g != gcur) {
                    if (gcur >= 0) atomicAdd(&embsum[gcur * HD + c], acc);
                    acc = 0.f;
                    gcur = g;
                }
                acc += hsf[r * 132 + c];
            }
            if (gcur >= 0) atomicAdd(&embsum[gcur * HD + c], acc);
        }
    }
}

// ---------------- head: emb = embsum/cnt; z = relu([emb|meta]@Wh1+bh1); out = z@Wh2+bh2 ----------------
__global__ __launch_bounds__(128) void k_head(const float* __restrict__ embsum, const int* __restrict__ batch,
                                              const float* __restrict__ meta,
                                              const float* __restrict__ Wh1, const float* __restrict__ bh1,
                                              const float* __restrict__ Wh2, const float* __restrict__ bh2,
                                              float* __restrict__ out) {
    int g = blockIdx.x;
    int c = threadIdx.x;
    int l = 0, r = NN;
    while (l < r) { int m = (l + r) >> 1; if (batch[m] < g) l = m + 1; else r = m; }
    int lo = l;
    r = NN;
    while (l < r) { int m = (l + r) >> 1; if (batch[m] < g + 1) l = m + 1; else r = m; }
    int hi = l;
    float rcp = 1.0f / (float)max(hi - lo, 1);

    __shared__ float emb[HD];
    __shared__ float mt[NMETA];
    emb[c] = embsum[g * HD + c] * rcp;
    if (c < NMETA) mt[c] = meta[g * NMETA + c];
    __syncthreads();

    float z = bh1[c];
    float z0 = 0.f, z1 = 0.f, z2 = 0.f, z3 = 0.f;
    for (int k = 0; k < HD; k += 4) {
        z0 = fmaf(emb[k],     Wh1[k * HD + c],       z0);
        z1 = fmaf(emb[k + 1], Wh1[(k + 1) * HD + c], z1);
        z2 = fmaf(emb[k + 2], Wh1[(k + 2) * HD + c], z2);
        z3 = fmaf(emb[k + 3], Wh1[(k + 3) * HD + c], z3);
    }
    for (int k = 0; k < NMETA; ++k) z = fmaf(mt[k], Wh1[(HD + k) * HD + c], z);
    z += (z0 + z1) + (z2 + z3);
    z = relu(z);
    __shared__ float red[HD];
    red[c] = z * Wh2[c];
    __syncthreads();
    for (int st = 64; st > 0; st >>= 1) {
        if (c < st) red[c] += red[c + st];
        __syncthreads();
    }
    if (c == 0) out[g] = red[0] + bh2[0];
}

extern "C" void kernel_launch(void* const* d_in, const int* in_sizes, int n_in,
                              void* d_out, int out_size, void* d_ws, size_t ws_size,
                              hipStream_t stream) {
    const float* x     = (const float*)d_in[0];
    const int*   ei    = (const int*)d_in[1];
    const int*   src   = ei;
    const int*   dst   = ei + NE;
    const int*   batch = (const int*)d_in[2];
    const float* meta  = (const float*)d_in[3];
    const float* W1 = (const float*)d_in[4];  const float* b1 = (const float*)d_in[5];
    const float* W2 = (const float*)d_in[6];  const float* b2 = (const float*)d_in[7];
    const float* W3 = (const float*)d_in[8];  const float* b3 = (const float*)d_in[9];
    const float* Wh1 = (const float*)d_in[10]; const float* bh1 = (const float*)d_in[11];
    const float* Wh2 = (const float*)d_in[12]; const float* bh2 = (const float*)d_in[13];
    float* out = (float*)d_out;

    // workspace layout (16B-aligned sections)
    int*   csr_src  = (int*)d_ws;                         // NE
    int*   cnt      = csr_src + NE;                       // NN
    int*   partial  = cnt + NN;                           // NN
    int*   blocksum = partial + NN;                       // 256
    int*   blockoff = blocksum + 256;                     // 256
    int*   rowptr   = blockoff + 256;                     // NN+1 (pad 8)
    int*   cursor   = rowptr + NN + 8;                    // NN
    float* dinv     = (float*)(cursor + NN);              // NN
    float* embsum   = dinv + NN;                          // NB*HD f32
    unsigned short* Ta  = (unsigned short*)(embsum + NB * HD);  // NN*HD bf16
    unsigned short* Tc  = Ta + (size_t)NN * HD;                 // NN*HD bf16
    unsigned short* Wt1 = Tc + (size_t)NN * HD;                 // HD*HD bf16
    unsigned short* Wt2 = Wt1 + HD * HD;
    unsigned short* Wt3 = Wt2 + HD * HD;

    const int GEMM_GRID  = (NN + 63) / 64;                // 782
    const int FUSED_GRID = (NN + 31) / 32;                // 1563
    const int CWT_GRID   = (3 * HD * HD + 255) / 256;     // 192

    // build CSR-by-dst
    hipMemsetAsync(cnt, 0, NN * sizeof(int), stream);
    hipMemsetAsync(embsum, 0, NB * HD * sizeof(float), stream);
    k_count<<<(NE + 255) / 256, 256, 0, stream>>>(dst, cnt);
    k_scanA<<<SCAN_BLOCKS, 256, 0, stream>>>(cnt, partial, blocksum, dinv);
    k_scanB<<<1, 256, 0, stream>>>(blocksum, blockoff);
    k_scanC<<<SCAN_BLOCKS, 256, 0, stream>>>(partial, blockoff, rowptr, cursor);
    k_fill<<<(NE + 255) / 256, 256, 0, stream>>>(src, dst, cursor, csr_src);

    k_castWt3<<<CWT_GRID, 256, 0, stream>>>(W1, W2, W3, Wt1, Wt2, Wt3);

    // layer 1: T1' = (cast(x) @ W1) * dinv
    k_gemm_x<<<GEMM_GRID, 256, 0, stream>>>(x, Wt1, dinv, Ta);
    // layer 1 gather + layer 2 gemm: T2'
    k_fused<1><<<FUSED_GRID, 512, 0, stream>>>(rowptr, csr_src, Ta, dinv, b1, Wt2, Tc, nullptr, nullptr);
    // layer 2 gather + layer 3 gemm: T3'
    k_fused<1><<<FUSED_GRID, 512, 0, stream>>>(rowptr, csr_src, Tc, dinv, b2, Wt3, Ta, nullptr, nullptr);
    // layer 3 gather + pooled segment-sum into embsum
    k_fused<2><<<FUSED_GRID, 512, 0, stream>>>(rowptr, csr_src, Ta, dinv, b3, nullptr, nullptr, batch, embsum);

    // head
    k_head<<<NB, 128, 0, stream>>>(embsum, batch, meta, Wh1, bh1, Wh2, bh2, out);
}

// Round 10
// 294.106 us; speedup vs baseline: 11.4515x; 1.0197x over previous
//
#include <hip/hip_runtime.h>

#define NN 50000
#define NE 600000
#define NB 512
#define HD 128
#define NMETA 27
#define SCAN_BLOCKS ((NN + 255) / 256)   // 196

typedef __attribute__((ext_vector_type(8))) short short8;   // 8 bf16 (16B)
typedef __attribute__((ext_vector_type(4))) float f32x4;    // C/D frag

__device__ __forceinline__ float relu(float x) { return fmaxf(x, 0.0f); }

// fp32 -> bf16 round-to-nearest-even
__device__ __forceinline__ unsigned short f2bf(float f) {
    unsigned u = __float_as_uint(f);
    unsigned r = u + 0x7FFFu + ((u >> 16) & 1u);
    return (unsigned short)(r >> 16);
}
__device__ __forceinline__ float bf2f(unsigned short v) {
    return __uint_as_float(((unsigned)v) << 16);
}

// ---------------- CSR build ----------------
__global__ __launch_bounds__(256) void k_count(const int* __restrict__ dst, int* __restrict__ cnt) {
    int i = blockIdx.x * 256 + threadIdx.x;
    if (i < NE) atomicAdd(&cnt[dst[i]], 1);
}

__global__ __launch_bounds__(256) void k_scanA(const int* __restrict__ cnt, int* __restrict__ partial,
                                               int* __restrict__ blocksum, float* __restrict__ dinv) {
    const int t = threadIdx.x;
    const int i = blockIdx.x * 256 + t;
    int v = (i < NN) ? cnt[i] : 0;
    if (i < NN) dinv[i] = rsqrtf((float)v + 1.0f);
    __shared__ int s[256];
    s[t] = v;
    __syncthreads();
    for (int off = 1; off < 256; off <<= 1) {
        int u = (t >= off) ? s[t - off] : 0;
        __syncthreads();
        s[t] += u;
        __syncthreads();
    }
    if (i < NN) partial[i] = s[t] - v;
    if (t == 255) blocksum[blockIdx.x] = s[255];
}

__global__ __launch_bounds__(256) void k_scanB(const int* __restrict__ blocksum, int* __restrict__ blockoff) {
    const int t = threadIdx.x;
    int v = (t < SCAN_BLOCKS) ? blocksum[t] : 0;
    __shared__ int s[256];
    s[t] = v;
    __syncthreads();
    for (int off = 1; off < 256; off <<= 1) {
        int u = (t >= off) ? s[t - off] : 0;
        __syncthreads();
        s[t] += u;
        __syncthreads();
    }
    if (t < SCAN_BLOCKS) blockoff[t] = s[t] - v;
}

__global__ __launch_bounds__(256) void k_scanC(const int* __restrict__ partial, const int* __restrict__ blockoff,
                                               int* __restrict__ rowptr, int* __restrict__ cursor) {
    const int i = blockIdx.x * 256 + threadIdx.x;
    if (i < NN) {
        int rp = partial[i] + blockoff[i >> 8];
        rowptr[i] = rp;
        cursor[i] = rp;
    }
    if (i == 0) rowptr[NN] = NE;
}

// fill CSR: src index only (norm factored into T' producer-side)
__global__ __launch_bounds__(256) void k_fill(const int* __restrict__ src, const int* __restrict__ dst,
                                              int* __restrict__ cursor, int* __restrict__ csr_src) {
    int e = blockIdx.x * 256 + threadIdx.x;
    if (e >= NE) return;
    int s = src[e], d = dst[e];
    int pos = atomicAdd(&cursor[d], 1);
    csr_src[pos] = s;
}

// all three W [128][128] f32 row-major (k,n) -> Wt bf16 [n][k], one launch
__global__ __launch_bounds__(256) void k_castWt3(const float* __restrict__ W1, const float* __restrict__ W2,
                                                 const float* __restrict__ W3, unsigned short* __restrict__ Wt1,
                                                 unsigned short* __restrict__ Wt2, unsigned short* __restrict__ Wt3) {
    int i = blockIdx.x * 256 + threadIdx.x;
    if (i >= 3 * HD * HD) return;
    int which = i / (HD * HD);
    int r = i - which * (HD * HD);
    int k = r >> 7, n = r & 127;
    const float* W = (which == 0) ? W1 : (which == 1) ? W2 : W3;
    unsigned short* Wt = (which == 0) ? Wt1 : (which == 1) ? Wt2 : Wt3;
    Wt[n * HD + k] = f2bf(W[r]);
}

// ---------------- layer-1 GEMM: T1' = (cast(x) @ W1) * dinv[row] ----------------
__global__ __launch_bounds__(256) void k_gemm_x(const float* __restrict__ X,
                                                const unsigned short* __restrict__ Wt,
                                                const float* __restrict__ dinv,
                                                unsigned short* __restrict__ T) {
    __shared__ unsigned short Ws[HD * HD];      // 32 KB
    char* wsb = (char*)Ws;
    for (int i = threadIdx.x; i < HD * HD / 8; i += 256) {
        short8 v = ((const short8*)Wt)[i];
        int byte = i * 16;
        *(short8*)(wsb + (byte ^ (((byte >> 8) & 7) << 4))) = v;
    }
    __syncthreads();

    const int wave = threadIdx.x >> 6;
    const int lane = threadIdx.x & 63;
    const int lr = lane & 15;
    const int kh = lane >> 4;
    const int r0 = blockIdx.x * 64 + wave * 16;
    const float* arow = X + (size_t)min(r0 + lr, NN - 1) * HD + kh * 8;

    f32x4 acc[8] = {};
#pragma unroll
    for (int kk = 0; kk < 4; ++kk) {
        float4 a0 = *reinterpret_cast<const float4*>(arow + kk * 32);
        float4 a1 = *reinterpret_cast<const float4*>(arow + kk * 32 + 4);
        short8 af;
        af[0] = (short)f2bf(a0.x); af[1] = (short)f2bf(a0.y);
        af[2] = (short)f2bf(a0.z); af[3] = (short)f2bf(a0.w);
        af[4] = (short)f2bf(a1.x); af[5] = (short)f2bf(a1.y);
        af[6] = (short)f2bf(a1.z); af[7] = (short)f2bf(a1.w);
#pragma unroll
        for (int n = 0; n < 8; ++n) {
            int byte = (n * 16 + lr) * 256 + kk * 64 + kh * 16;
            short8 bf = *(const short8*)(wsb + (byte ^ (((byte >> 8) & 7) << 4)));
            acc[n] = __builtin_amdgcn_mfma_f32_16x16x32_bf16(af, bf, acc[n], 0, 0, 0);
        }
    }
    float dv[4];
#pragma unroll
    for (int r = 0; r < 4; ++r) {
        int row = r0 + kh * 4 + r;
        dv[r] = (row < NN) ? dinv[row] : 0.0f;
    }
#pragma unroll
    for (int n = 0; n < 8; ++n) {
#pragma unroll
        for (int r = 0; r < 4; ++r) {
            int row = r0 + kh * 4 + r;
            if (row < NN) T[(size_t)row * HD + n * 16 + lr] = f2bf(acc[n][r] * dv[r]);
        }
    }
}

// ---------------- fused gather -> {GEMM | POOL} ----------------
// 512 thr = 8 waves, 32 rows/block, grid = ceil(NN/32) = 1563.
// Gather: 16 lanes/row, ONE 16B load per lane per edge (8 consecutive cols).
// H[row] = relu( dinv[row]*(sum_e T'[src_e] + T'[row]) + b ), T' pre-scaled.
// MODE 1: H (bf16, swizzled LDS) -> T_out' = (H @ Wt)*dinv  (2 row-tiles x 8 col-tiles)
// MODE 2: H (fp32, padded LDS) -> sorted-batch segment-reduce -> atomicAdd embsum
template <int MODE>
__global__ __launch_bounds__(512, 8) void k_fused(const int* __restrict__ rowptr, const int* __restrict__ csr_src,
                                                  const unsigned short* __restrict__ Tin, const float* __restrict__ dinv,
                                                  const float* __restrict__ b, const unsigned short* __restrict__ Wt,
                                                  unsigned short* __restrict__ Out, const int* __restrict__ batch,
                                                  float* __restrict__ embsum) {
    __shared__ char smem[32 * 132 * 4 + 128];   // fp32 padded tile + sg[32]
    char* hsb = smem;                            // MODE1: bf16 swizzled in first 8KB
    float* hsf = (float*)smem;                   // MODE2: [32][132] fp32
    int* sg = (int*)(smem + 32 * 132 * 4);

    const int rl  = threadIdx.x >> 4;           // 0..31 row within tile
    const int l16 = threadIdx.x & 15;
    const int row = blockIdx.x * 32 + rl;
    const int c   = l16 * 8;                    // 8 consecutive cols, 16B

    if (MODE == 2 && threadIdx.x < 32) {
        int rr = blockIdx.x * 32 + threadIdx.x;
        sg[threadIdx.x] = (rr < NN) ? batch[rr] : -1;
    }

    float acc[8] = {};

    if (row < NN) {
        const int lo = rowptr[row], hi = rowptr[row + 1];
        int j = lo;
        int sA0, sA1, sA2, sA3, sB0, sB1, sB2, sB3;
        bool haveA = (j + 3 < hi);
        if (haveA) { sA0 = csr_src[j]; sA1 = csr_src[j + 1]; sA2 = csr_src[j + 2]; sA3 = csr_src[j + 3]; }
        while (haveA) {
            const int jn = j + 4;
            const bool haveB = (jn + 3 < hi);
            if (haveB) { sB0 = csr_src[jn]; sB1 = csr_src[jn + 1]; sB2 = csr_src[jn + 2]; sB3 = csr_src[jn + 3]; }
            short8 t0 = *reinterpret_cast<const short8*>(Tin + (size_t)sA0 * HD + c);
            short8 t1 = *reinterpret_cast<const short8*>(Tin + (size_t)sA1 * HD + c);
            short8 t2 = *reinterpret_cast<const short8*>(Tin + (size_t)sA2 * HD + c);
            short8 t3 = *reinterpret_cast<const short8*>(Tin + (size_t)sA3 * HD + c);
#pragma unroll
            for (int i = 0; i < 8; ++i) {
                acc[i] += bf2f((unsigned short)t0[i]);
                acc[i] += bf2f((unsigned short)t1[i]);
                acc[i] += bf2f((unsigned short)t2[i]);
                acc[i] += bf2f((unsigned short)t3[i]);
            }
            j = jn;
            sA0 = sB0; sA1 = sB1; sA2 = sB2; sA3 = sB3;
            haveA = haveB;
        }
        for (; j < hi; ++j) {
            int s = csr_src[j];
            short8 tv = *reinterpret_cast<const short8*>(Tin + (size_t)s * HD + c);
#pragma unroll
            for (int i = 0; i < 8; ++i) acc[i] += bf2f((unsigned short)tv[i]);
        }
        const float di = dinv[row];
        short8 ts = *reinterpret_cast<const short8*>(Tin + (size_t)row * HD + c);
        float4 bb0 = *reinterpret_cast<const float4*>(b + c);
        float4 bb1 = *reinterpret_cast<const float4*>(b + c + 4);
        float h[8];
#pragma unroll
        for (int i = 0; i < 8; ++i) {
            float bbv = (i < 4) ? (&bb0.x)[i] : (&bb1.x)[i - 4];
            h[i] = relu(fmaf(di, acc[i] + bf2f((unsigned short)ts[i]), bbv));
        }
        if (MODE == 1) {
            short8 o;
#pragma unroll
            for (int i = 0; i < 8; ++i) o[i] = (short)f2bf(h[i]);
            int byte0 = rl * 256 + c * 2;       // 16B aligned
            *(short8*)(hsb + (byte0 ^ (((byte0 >> 8) & 7) << 4))) = o;
        } else {
            *(float4*)(&hsf[rl * 132 + c])     = make_float4(h[0], h[1], h[2], h[3]);
            *(float4*)(&hsf[rl * 132 + c + 4]) = make_float4(h[4], h[5], h[6], h[7]);
        }
    } else {
        if (MODE == 1) {
            short8 z = {0, 0, 0, 0, 0, 0, 0, 0};
            int byte0 = rl * 256 + c * 2;
            *(short8*)(hsb + (byte0 ^ (((byte0 >> 8) & 7) << 4))) = z;
        } else {
            float4 z = make_float4(0.f, 0.f, 0.f, 0.f);
            *(float4*)(&hsf[rl * 132 + c])     = z;
            *(float4*)(&hsf[rl * 132 + c + 4]) = z;
        }
    }
    __syncthreads();

    if (MODE == 1) {
        // T_out' = (H @ Wt) * dinv
        const int w = threadIdx.x >> 6;       // col-tile 0..7
        const int lane = threadIdx.x & 63;
        const int lr = lane & 15;
        const int kh = lane >> 4;
        f32x4 acc0 = {}, acc1 = {};
#pragma unroll
        for (int kk = 0; kk < 4; ++kk) {
            short8 bf = *reinterpret_cast<const short8*>(Wt + (size_t)(w * 16 + lr) * HD + kk * 32 + kh * 8);
            int byteA = lr * 256 + kk * 64 + kh * 16;
            int byteB = (16 + lr) * 256 + kk * 64 + kh * 16;
            short8 af0 = *(const short8*)(hsb + (byteA ^ (((byteA >> 8) & 7) << 4)));
            short8 af1 = *(const short8*)(hsb + (byteB ^ (((byteB >> 8) & 7) << 4)));
            acc0 = __builtin_amdgcn_mfma_f32_16x16x32_bf16(af0, bf, acc0, 0, 0, 0);
            acc1 = __builtin_amdgcn_mfma_f32_16x16x32_bf16(af1, bf, acc1, 0, 0, 0);
        }
#pragma unroll
        for (int r = 0; r < 4; ++r) {
            int row0 = blockIdx.x * 32 + kh * 4 + r;
            int row1 = row0 + 16;
            if (row0 < NN) Out[(size_t)row0 * HD + w * 16 + lr] = f2bf(acc0[r] * dinv[row0]);
            if (row1 < NN) Out[(size_t)row1 * HD + w * 16 + lr] = f2bf(acc1[r] * dinv[row1]);
        }
    } else {
        // segment-reduce 32 sorted rows -> atomicAdd into embsum
        if (threadIdx.x < HD) {
            const int cc = threadIdx.x;
            float a = 0.f;
            int gcur = -1;
#pragma unroll 8
            for (int r = 0; r < 32; ++r) {
                int g = sg[r];
                if (g != gcur) {
                    if (gcur >= 0) atomicAdd(&embsum[gcur * HD + cc], a);
                    a = 0.f;
                    gcur = g;
                }
                a += hsf[r * 132 + cc];
            }
            if (gcur >= 0) atomicAdd(&embsum[gcur * HD + cc], a);
        }
    }
}

// ---------------- head ----------------
__global__ __launch_bounds__(128) void k_head(const float* __restrict__ embsum, const int* __restrict__ batch,
                                              const float* __restrict__ meta,
                                              const float* __restrict__ Wh1, const float* __restrict__ bh1,
                                              const float* __restrict__ Wh2, const float* __restrict__ bh2,
                                              float* __restrict__ out) {
    int g = blockIdx.x;
    int c = threadIdx.x;
    int l = 0, r = NN;
    while (l < r) { int m = (l + r) >> 1; if (batch[m] < g) l = m + 1; else r = m; }
    int lo = l;
    r = NN;
    while (l < r) { int m = (l + r) >> 1; if (batch[m] < g + 1) l = m + 1; else r = m; }
    int hi = l;
    float rcp = 1.0f / (float)max(hi - lo, 1);

    __shared__ float emb[HD];
    __shared__ float mt[NMETA];
    emb[c] = embsum[g * HD + c] * rcp;
    if (c < NMETA) mt[c] = meta[g * NMETA + c];
    __syncthreads();

    float z = bh1[c];
    float z0 = 0.f, z1 = 0.f, z2 = 0.f, z3 = 0.f;
    for (int k = 0; k < HD; k += 4) {
        z0 = fmaf(emb[k],     Wh1[k * HD + c],       z0);
        z1 = fmaf(emb[k + 1], Wh1[(k + 1) * HD + c], z1);
        z2 = fmaf(emb[k + 2], Wh1[(k + 2) * HD + c], z2);
        z3 = fmaf(emb[k + 3], Wh1[(k + 3) * HD + c], z3);
    }
    for (int k = 0; k < NMETA; ++k) z = fmaf(mt[k], Wh1[(HD + k) * HD + c], z);
    z += (z0 + z1) + (z2 + z3);
    z = relu(z);
    __shared__ float red[HD];
    red[c] = z * Wh2[c];
    __syncthreads();
    for (int st = 64; st > 0; st >>= 1) {
        if (c < st) red[c] += red[c + st];
        __syncthreads();
    }
    if (c == 0) out[g] = red[0] + bh2[0];
}

extern "C" void kernel_launch(void* const* d_in, const int* in_sizes, int n_in,
                              void* d_out, int out_size, void* d_ws, size_t ws_size,
                              hipStream_t stream) {
    const float* x     = (const float*)d_in[0];
    const int*   ei    = (const int*)d_in[1];
    const int*   src   = ei;
    const int*   dst   = ei + NE;
    const int*   batch = (const int*)d_in[2];
    const float* meta  = (const float*)d_in[3];
    const float* W1 = (const float*)d_in[4];  const float* b1 = (const float*)d_in[5];
    const float* W2 = (const float*)d_in[6];  const float* b2 = (const float*)d_in[7];
    const float* W3 = (const float*)d_in[8];  const float* b3 = (const float*)d_in[9];
    const float* Wh1 = (const float*)d_in[10]; const float* bh1 = (const float*)d_in[11];
    const float* Wh2 = (const float*)d_in[12]; const float* bh2 = (const float*)d_in[13];
    float* out = (float*)d_out;

    // workspace layout (16B-aligned sections)
    int*   csr_src  = (int*)d_ws;                         // NE
    int*   cnt      = csr_src + NE;                       // NN
    int*   partial  = cnt + NN;                           // NN
    int*   blocksum = partial + NN;                       // 256
    int*   blockoff = blocksum + 256;                     // 256
    int*   rowptr   = blockoff + 256;                     // NN+1 (pad 8)
    int*   cursor   = rowptr + NN + 8;                    // NN
    float* dinv     = (float*)(cursor + NN);              // NN
    float* embsum   = dinv + NN;                          // NB*HD f32
    unsigned short* Ta  = (unsigned short*)(embsum + NB * HD);  // NN*HD bf16
    unsigned short* Tc  = Ta + (size_t)NN * HD;                 // NN*HD bf16
    unsigned short* Wt1 = Tc + (size_t)NN * HD;                 // HD*HD bf16
    unsigned short* Wt2 = Wt1 + HD * HD;
    unsigned short* Wt3 = Wt2 + HD * HD;

    const int GEMM_GRID  = (NN + 63) / 64;                // 782
    const int FUSED_GRID = (NN + 31) / 32;                // 1563
    const int CWT_GRID   = (3 * HD * HD + 255) / 256;     // 192

    // build CSR-by-dst
    hipMemsetAsync(cnt, 0, NN * sizeof(int), stream);
    hipMemsetAsync(embsum, 0, NB * HD * sizeof(float), stream);
    k_count<<<(NE + 255) / 256, 256, 0, stream>>>(dst, cnt);
    k_scanA<<<SCAN_BLOCKS, 256, 0, stream>>>(cnt, partial, blocksum, dinv);
    k_scanB<<<1, 256, 0, stream>>>(blocksum, blockoff);
    k_scanC<<<SCAN_BLOCKS, 256, 0, stream>>>(partial, blockoff, rowptr, cursor);
    k_fill<<<(NE + 255) / 256, 256, 0, stream>>>(src, dst, cursor, csr_src);

    k_castWt3<<<CWT_GRID, 256, 0, stream>>>(W1, W2, W3, Wt1, Wt2, Wt3);

    // layer 1: T1' = (cast(x) @ W1) * dinv
    k_gemm_x<<<GEMM_GRID, 256, 0, stream>>>(x, Wt1, dinv, Ta);
    // layer 1 gather + layer 2 gemm: T2'
    k_fused<1><<<FUSED_GRID, 512, 0, stream>>>(rowptr, csr_src, Ta, dinv, b1, Wt2, Tc, nullptr, nullptr);
    // layer 2 gather + layer 3 gemm: T3'
    k_fused<1><<<FUSED_GRID, 512, 0, stream>>>(rowptr, csr_src, Tc, dinv, b2, Wt3, Ta, nullptr, nullptr);
    // layer 3 gather + pooled segment-sum into embsum
    k_fused<2><<<FUSED_GRID, 512, 0, stream>>>(rowptr, csr_src, Ta, dinv, b3, nullptr, nullptr, batch, embsum);

    // head
    k_head<<<NB, 128, 0, stream>>>(embsum, batch, meta, Wh1, bh1, Wh2, bh2, out);
}